// Round 2
// baseline (2317.442 us; speedup 1.0000x reference)
//
#include <hip/hip_runtime.h>

typedef _Float16 half8 __attribute__((ext_vector_type(8)));
typedef float floatx4 __attribute__((ext_vector_type(4)));

#define B_    64
#define N_    512
#define DIN_  256
#define DH_   512
#define DOUT_ 256
#define H_    4
#define BN_   (B_ * N_)   // 32768
#define CHUNK 32          // batches per attention-pipeline chunk
#define NCH   (B_ / CHUNK)

// ---------------------------------------------------------------------------
// async global->LDS 16B copy (gfx950). LDS dest must be wave-uniform;
// HW writes lane i's 16B to lds_base + i*16.
// ---------------------------------------------------------------------------
__device__ static inline void async_copy16(const _Float16* g, _Float16* l) {
    __builtin_amdgcn_global_load_lds(
        (const __attribute__((address_space(1))) void*)g,
        (__attribute__((address_space(3))) void*)l, 16, 0, 0);
}

// ---------------------------------------------------------------------------
// GEMM: C[M,N] = A[M,K] * B[N,K]^T  (+bias, + optional accumulate into C)
// A,B fp16 row-major, leading dims along K. Tile 128x128, BK=32, 4 waves,
// each wave 64x64 via 4x4 MFMA 16x16x32 f16.  M%128==N%128==0, K%32==0.
// biasMode: 0=none, 1=bias[col], 2=bias[row]
// ---------------------------------------------------------------------------
template <bool OUT_F16>
__global__ __launch_bounds__(256)
void gemm_f16(const _Float16* __restrict__ A, long long aStride, int lda,
              const _Float16* __restrict__ B, long long bStride, int ldb,
              void* __restrict__ Cv, long long cStride, int ldc,
              int K, const float* __restrict__ bias, int biasMode, int beta)
{
    __shared__ __align__(16) _Float16 As[128 * 32];
    __shared__ __align__(16) _Float16 Bs[128 * 32];

    const int tid  = threadIdx.x;
    const int wave = tid >> 6;
    const int lane = tid & 63;
    const int quad = lane >> 4;     // 0..3
    const int r16  = lane & 15;     // 0..15
    const int z    = blockIdx.z;
    const int m0   = blockIdx.y * 128;
    const int n0   = blockIdx.x * 128;

    const _Float16* Ab = A + (long long)z * aStride;
    const _Float16* Bb = B + (long long)z * bStride;

    // staging: each wave covers 32 rows of each tile via 2 instructions.
    const int srow = lane >> 2;        // 0..15
    const int scol = (lane & 3) * 8;   // element offset along K
    const _Float16* ga = Ab + (size_t)(m0 + wave * 32 + srow) * lda + scol;
    const _Float16* gb = Bb + (size_t)(n0 + wave * 32 + srow) * ldb + scol;
    _Float16* lA = &As[(wave * 32) * 32];
    _Float16* lB = &Bs[(wave * 32) * 32];

    const int wm = (wave >> 1) * 64;
    const int wn = (wave & 1) * 64;

    floatx4 acc[4][4];
#pragma unroll
    for (int i = 0; i < 4; i++)
#pragma unroll
        for (int j = 0; j < 4; j++) acc[i][j] = (floatx4){0.f, 0.f, 0.f, 0.f};

    for (int k0 = 0; k0 < K; k0 += 32) {
        async_copy16(ga + k0,                    lA);
        async_copy16(ga + k0 + (size_t)16 * lda, lA + 16 * 32);
        async_copy16(gb + k0,                    lB);
        async_copy16(gb + k0 + (size_t)16 * ldb, lB + 16 * 32);
        __syncthreads();

        half8 af[4], bf[4];
#pragma unroll
        for (int i = 0; i < 4; i++)
            af[i] = *(const half8*)&As[(wm + i * 16 + r16) * 32 + quad * 8];
#pragma unroll
        for (int j = 0; j < 4; j++)
            bf[j] = *(const half8*)&Bs[(wn + j * 16 + r16) * 32 + quad * 8];

#pragma unroll
        for (int i = 0; i < 4; i++)
#pragma unroll
            for (int j = 0; j < 4; j++)
                acc[i][j] = __builtin_amdgcn_mfma_f32_16x16x32_f16(
                    af[i], bf[j], acc[i][j], 0, 0, 0);
        __syncthreads();
    }

    // epilogue: C/D layout col = lane&15, row = quad*4 + reg  [m89-verified]
    float*    Cf = (float*)Cv    + (long long)z * cStride;
    _Float16* Ch = (_Float16*)Cv + (long long)z * cStride;
#pragma unroll
    for (int i = 0; i < 4; i++) {
#pragma unroll
        for (int j = 0; j < 4; j++) {
#pragma unroll
            for (int r = 0; r < 4; r++) {
                const int row = m0 + wm + i * 16 + quad * 4 + r;
                const int col = n0 + wn + j * 16 + r16;
                float v = acc[i][j][r];
                if (biasMode == 1)      v += bias[col];
                else if (biasMode == 2) v += bias[row];
                const size_t idx = (size_t)row * ldc + col;
                if (OUT_F16) {
                    if (beta) v += (float)Ch[idx];
                    Ch[idx] = (_Float16)v;
                } else {
                    if (beta) v += Cf[idx];
                    Cf[idx] = v;
                }
            }
        }
    }
}

// ---------------------------------------------------------------------------
// in-place softmax over rows of S[nrows, 512] (fp32), scaled by 0.25
// (head mean). Writes fp16 result into the FIRST 1024 bytes of the same row.
// One wave per row; all reads complete (registers) before any store.
// ---------------------------------------------------------------------------
__global__ __launch_bounds__(256)
void softmax_inplace(float* __restrict__ S)
{
    const int row  = blockIdx.x * 4 + (threadIdx.x >> 6);
    const int lane = threadIdx.x & 63;
    float* s = S + (size_t)row * 512;

    float v[8];
    float mx = -1e30f;
#pragma unroll
    for (int j = 0; j < 8; j++) {
        v[j] = s[lane + j * 64];
        mx = fmaxf(mx, v[j]);
    }
#pragma unroll
    for (int off = 32; off; off >>= 1) mx = fmaxf(mx, __shfl_xor(mx, off));
    float sum = 0.f;
#pragma unroll
    for (int j = 0; j < 8; j++) {
        v[j] = __expf(v[j] - mx);
        sum += v[j];
    }
#pragma unroll
    for (int off = 32; off; off >>= 1) sum += __shfl_xor(sum, off);
    const float inv = 0.25f / sum;
    _Float16* p = (_Float16*)s;
#pragma unroll
    for (int j = 0; j < 8; j++) p[lane + j * 64] = (_Float16)(v[j] * inv);
}

// ---------------------------------------------------------------------------
// fp32 -> fp16 convert, 4 elems/thread
// ---------------------------------------------------------------------------
__global__ __launch_bounds__(256)
void cvt_f32_f16(const float* __restrict__ in, _Float16* __restrict__ out)
{
    const size_t i = ((size_t)blockIdx.x * blockDim.x + threadIdx.x) * 4;
    const float4 f = *(const float4*)(in + i);
    out[i + 0] = (_Float16)f.x;
    out[i + 1] = (_Float16)f.y;
    out[i + 2] = (_Float16)f.z;
    out[i + 3] = (_Float16)f.w;
}

// ---------------------------------------------------------------------------
// batched transpose + fp32->fp16: in [G][R][C] -> out [G][C][R]
// grid (C/32, R/32, G), block (32, 8)
// ---------------------------------------------------------------------------
__global__ __launch_bounds__(256)
void transpose_cvt(const float* __restrict__ in, _Float16* __restrict__ out,
                   int R, int C)
{
    __shared__ float tile[32][33];
    const int g  = blockIdx.z;
    const int c0 = blockIdx.x * 32;
    const int r0 = blockIdx.y * 32;
    const float* inp  = in  + (size_t)g * R * C;
    _Float16*    outp = out + (size_t)g * R * C;
#pragma unroll
    for (int i = threadIdx.y; i < 32; i += 8)
        tile[i][threadIdx.x] = inp[(size_t)(r0 + i) * C + c0 + threadIdx.x];
    __syncthreads();
#pragma unroll
    for (int i = threadIdx.y; i < 32; i += 8)
        outp[(size_t)(c0 + i) * R + r0 + threadIdx.x] = (_Float16)tile[threadIdx.x][i];
}

// ---------------------------------------------------------------------------
extern "C" void kernel_launch(void* const* d_in, const int* in_sizes, int n_in,
                              void* d_out, int out_size, void* d_ws, size_t ws_size,
                              hipStream_t stream)
{
    (void)in_sizes; (void)n_in; (void)out_size; (void)ws_size;

    const float* x      = (const float*)d_in[0];
    const float* e_w0   = (const float*)d_in[1];
    const float* e_b0   = (const float*)d_in[2];
    const float* kq_w0  = (const float*)d_in[3];
    const float* kq_b0  = (const float*)d_in[4];
    const float* e_w1   = (const float*)d_in[5];
    const float* e_b1   = (const float*)d_in[6];
    const float* kq_w1  = (const float*)d_in[7];
    const float* kq_b1  = (const float*)d_in[8];
    const float* proj_w = (const float*)d_in[9];
    const float* proj_b = (const float*)d_in[10];
    float* out = (float*)d_out;

    char* ws = (char*)d_ws;
    size_t off = 0;
    auto alloc = [&](size_t bytes) -> char* {
        char* p = ws + off;
        off += (bytes + 255) & ~(size_t)255;
        return p;
    };

    // total ws footprint ~= 178 MB
    _Float16* x16    = (_Float16*)alloc((size_t)BN_ * DIN_ * 2);            // 16.8 MB
    _Float16* h1_16  = (_Float16*)alloc((size_t)BN_ * DH_ * 2);             // 33.5 MB
    _Float16* h2_16  = (_Float16*)alloc((size_t)BN_ * DH_ * 2);             // 33.5 MB
    _Float16* ewT0   = (_Float16*)alloc((size_t)H_ * DH_ * DIN_ * 2);       //  1.0 MB
    _Float16* kqwT0  = (_Float16*)alloc((size_t)H_ * 2 * DH_ * DIN_ * 2);   //  2.1 MB
    _Float16* ewT1   = (_Float16*)alloc((size_t)H_ * DH_ * DH_ * 2);        //  2.1 MB
    _Float16* kqwT1  = (_Float16*)alloc((size_t)H_ * 2 * DH_ * DH_ * 2);    //  4.2 MB
    _Float16* projwT = (_Float16*)alloc((size_t)DOUT_ * DH_ * 2);           //  0.3 MB
    _Float16* kqc    = (_Float16*)alloc((size_t)CHUNK * N_ * 2 * DH_ * 2);  // 33.5 MB
    _Float16* embTc  = (_Float16*)alloc((size_t)CHUNK * DH_ * N_ * 2);      // 16.8 MB
    float*    Sc     = (float*)alloc((size_t)CHUNK * N_ * N_ * 4);          // 33.5 MB

    auto gemm = [&](bool outF16, const _Float16* A, long long aS, int lda,
                    const _Float16* Bp, long long bS, int ldb,
                    void* C, long long cS, int ldc,
                    int M, int Nn, int K, int batches,
                    const float* bias, int biasMode, int beta) {
        dim3 grid(Nn / 128, M / 128, batches), block(256);
        if (outF16)
            gemm_f16<true><<<grid, block, 0, stream>>>(A, aS, lda, Bp, bS, ldb,
                                                       C, cS, ldc, K, bias, biasMode, beta);
        else
            gemm_f16<false><<<grid, block, 0, stream>>>(A, aS, lda, Bp, bS, ldb,
                                                        C, cS, ldc, K, bias, biasMode, beta);
    };

    // --- input + weight preprocessing -------------------------------------
    cvt_f32_f16<<<BN_ * DIN_ / 1024, 256, 0, stream>>>(x, x16);
    transpose_cvt<<<dim3(DH_ / 32, DIN_ / 32, H_), dim3(32, 8), 0, stream>>>(e_w0, ewT0, DIN_, DH_);
    transpose_cvt<<<dim3(2 * DH_ / 32, DIN_ / 32, H_), dim3(32, 8), 0, stream>>>(kq_w0, kqwT0, DIN_, 2 * DH_);
    transpose_cvt<<<dim3(DH_ / 32, DH_ / 32, H_), dim3(32, 8), 0, stream>>>(e_w1, ewT1, DH_, DH_);
    transpose_cvt<<<dim3(2 * DH_ / 32, DH_ / 32, H_), dim3(32, 8), 0, stream>>>(kq_w1, kqwT1, DH_, 2 * DH_);
    transpose_cvt<<<dim3(DOUT_ / 32, DH_ / 32, 1), dim3(32, 8), 0, stream>>>(proj_w, projwT, DH_, DOUT_);

    // --- two attention blocks ---------------------------------------------
    for (int blk = 0; blk < 2; blk++) {
        const _Float16* xin  = blk ? h1_16 : x16;
        const int       Kin  = blk ? DH_ : DIN_;
        const _Float16* ewT  = blk ? ewT1 : ewT0;
        const _Float16* kqwT = blk ? kqwT1 : kqwT0;
        const float*    eb   = blk ? e_b1 : e_b0;
        const float*    kqb  = blk ? kq_b1 : kq_b0;
        _Float16*       hout = blk ? h2_16 : h1_16;

        for (int c = 0; c < NCH; c++) {
            const _Float16* xc = xin  + (size_t)c * CHUNK * N_ * Kin;
            _Float16*       hc = hout + (size_t)c * CHUNK * N_ * DH_;

            for (int h = 0; h < H_; h++) {
                // kq[bn, f] = x @ kq_w[h] + kq_b[h]  (K: cols 0..511, Q: 512..1023)
                gemm(true, xc, 0, Kin,
                     kqwT + (size_t)h * 2 * DH_ * Kin, 0, Kin,
                     kqc, 0, 2 * DH_,
                     CHUNK * N_, 2 * DH_, Kin, 1, kqb + (size_t)h * 2 * DH_, 1, 0);
                // embT[b][e][n] = W_e[h]^T x_b^T + e_b[h][e]
                gemm(true, ewT + (size_t)h * DH_ * Kin, 0, Kin,
                     xc, (long long)N_ * Kin, Kin,
                     embTc, (long long)DH_ * N_, N_,
                     DH_, N_, Kin, CHUNK, eb + (size_t)h * DH_, 2, 0);
                // S[b][q][k] = Q_b K_b^T  (fp32)
                gemm(false, kqc + DH_, (long long)N_ * 2 * DH_, 2 * DH_,
                     kqc, (long long)N_ * 2 * DH_, 2 * DH_,
                     Sc, (long long)N_ * N_, N_,
                     N_, N_, DH_, CHUNK, nullptr, 0, 0);
                // P = softmax(S) * 0.25, fp16, in place (row stride 1024 halves)
                softmax_inplace<<<CHUNK * N_ / 4, 256, 0, stream>>>(Sc);
                // h[b][q][e] += P_b @ embT_b^T  (fp16 accumulate over heads)
                gemm(true, (const _Float16*)Sc, (long long)N_ * 1024, 1024,
                     embTc, (long long)DH_ * N_, N_,
                     hc, (long long)N_ * DH_, DH_,
                     N_, DH_, N_, CHUNK, nullptr, 0, h > 0);
            }
        }
    }

    // --- output projection -------------------------------------------------
    gemm(false, h2_16, 0, DH_,
         projwT, 0, DH_,
         out, 0, DOUT_,
         BN_, DOUT_, DH_, 1, proj_b, 1, 0);
}

// Round 3
// 1872.126 us; speedup vs baseline: 1.2379x; 1.2379x over previous
//
#include <hip/hip_runtime.h>

typedef _Float16 half8 __attribute__((ext_vector_type(8)));
typedef float floatx4 __attribute__((ext_vector_type(4)));

#define B_    64
#define N_    512
#define DIN_  256
#define DH_   512
#define DOUT_ 256
#define H_    4
#define BN_   (B_ * N_)   // 32768

// raw waitcnt immediates (gfx9 encoding: vmcnt[3:0]|[15:14], exp[6:4], lgkm[11:8])
#define WAIT_VM4()   __builtin_amdgcn_s_waitcnt(0x0F74)  // vmcnt<=4, lgkm/exp free
#define WAIT_VM0()   __builtin_amdgcn_s_waitcnt(0x0F70)  // vmcnt<=0
#define WAIT_LGKM0() __builtin_amdgcn_s_waitcnt(0xC07F)  // lgkmcnt<=0, vm free
#define MEMBAR()     __asm__ __volatile__("" ::: "memory")

__device__ static inline void async_copy16(const _Float16* g, _Float16* l) {
    __builtin_amdgcn_global_load_lds(
        (const __attribute__((address_space(1))) void*)g,
        (__attribute__((address_space(3))) void*)l, 16, 0, 0);
}

// ---------------------------------------------------------------------------
// GEMM: C[M,N] = A[M,K] * B[N,K]^T (+bias). fp16 in, fp16/fp32 out.
// Segmented K: element (row, k) of A at  z1*aS1 + z2*aS2 + row*lda
//              + (k>>9)*aSeg + (k&511)   (aSeg=anything when K<=512).
// z = blockIdx.z; z1 = z>>zShift, z2 = z & ((1<<zShift)-1).
// Tile 128x128, BK=32, 4 waves, 4x4 MFMA 16x16x32 f16 per wave.
// Double-buffered LDS pipeline with raw vmcnt(4) waits (never full drain
// mid-loop). XCD swizzle on (x,y) for L2 tile reuse.
// biasMode: 0 none, 1 bias[col], 2 bias[row]; bias += z2*biasS2.
// ---------------------------------------------------------------------------
template <bool OUT_F16>
__global__ __launch_bounds__(256)
void gemm_f16(const _Float16* __restrict__ A, long long aS1, long long aS2, int lda, long long aSeg,
              const _Float16* __restrict__ B, long long bS1, long long bS2, int ldb, long long bSeg,
              void* __restrict__ Cv, long long cS1, long long cS2, int ldc,
              int K, const float* __restrict__ bias, int biasMode, int biasS2, int zShift)
{
    __shared__ __align__(16) _Float16 As[2][128 * 32];
    __shared__ __align__(16) _Float16 Bs[2][128 * 32];

    const int tid  = threadIdx.x;
    const int wave = tid >> 6;
    const int lane = tid & 63;
    const int quad = lane >> 4;
    const int r16  = lane & 15;

    const int z  = blockIdx.z;
    const int z1 = z >> zShift;
    const int z2 = z & ((1 << zShift) - 1);

    // XCD-aware swizzle: round-robin dispatch => same-XCD blocks get a
    // contiguous id2 range => they share A row-tiles (L2 locality).
    const int gx = gridDim.x, gy = gridDim.y;
    const int T = gx * gy;
    int lin = blockIdx.y * gx + blockIdx.x;
    int id2 = (T & 7) ? lin : ((lin & 7) * (T >> 3) + (lin >> 3));
    const int m0 = (id2 / gx) * 128;
    const int n0 = (id2 % gx) * 128;

    const int srow = lane >> 2;        // 0..15
    const int scol = (lane & 3) * 8;   // k offset within tile

    const _Float16* gaRow = A + z1 * aS1 + z2 * aS2
                              + (long long)(m0 + wave * 32 + srow) * lda + scol;
    const _Float16* gbRow = B + z1 * bS1 + z2 * bS2
                              + (long long)(n0 + wave * 32 + srow) * ldb + scol;

    const int wm = (wave >> 1) * 64;
    const int wn = (wave & 1) * 64;

    floatx4 acc[4][4];
#pragma unroll
    for (int i = 0; i < 4; i++)
#pragma unroll
        for (int j = 0; j < 4; j++) acc[i][j] = (floatx4){0.f, 0.f, 0.f, 0.f};

    auto stage = [&](int p, int k0) {
        const _Float16* a = gaRow + (long long)(k0 >> 9) * aSeg + (k0 & 511);
        const _Float16* b = gbRow + (long long)(k0 >> 9) * bSeg + (k0 & 511);
        _Float16* la = &As[p][wave * 1024];
        _Float16* lb = &Bs[p][wave * 1024];
        async_copy16(a,                    la);
        async_copy16(a + (size_t)16 * lda, la + 512);
        async_copy16(b,                    lb);
        async_copy16(b + (size_t)16 * ldb, lb + 512);
    };

    auto compute = [&](int p) {
        half8 af[4], bf[4];
#pragma unroll
        for (int i = 0; i < 4; i++)
            af[i] = *(const half8*)&As[p][(wm + i * 16 + r16) * 32 + quad * 8];
#pragma unroll
        for (int j = 0; j < 4; j++)
            bf[j] = *(const half8*)&Bs[p][(wn + j * 16 + r16) * 32 + quad * 8];
#pragma unroll
        for (int i = 0; i < 4; i++)
#pragma unroll
            for (int j = 0; j < 4; j++)
                acc[i][j] = __builtin_amdgcn_mfma_f32_16x16x32_f16(
                    af[i], bf[j], acc[i][j], 0, 0, 0);
    };

    const int niter = K >> 5;
    stage(0, 0);
    for (int it = 0; it < niter - 1; ++it) {
        stage((it + 1) & 1, (it + 1) << 5);             // prefetch next (vm +4)
        MEMBAR(); WAIT_VM4();                            // oldest 4 (cur) done
        __builtin_amdgcn_s_barrier(); MEMBAR();
        compute(it & 1);
        MEMBAR(); WAIT_LGKM0();                          // my LDS reads landed
        __builtin_amdgcn_s_barrier(); MEMBAR();          // before cur is reused
    }
    MEMBAR(); WAIT_VM0();
    __builtin_amdgcn_s_barrier(); MEMBAR();
    compute((niter - 1) & 1);

    // epilogue: C/D layout col = lane&15, row = quad*4 + reg
    const float* bz = bias + (long long)z2 * biasS2;
    float*    Cf = (float*)Cv    + z1 * cS1 + z2 * cS2;
    _Float16* Ch = (_Float16*)Cv + z1 * cS1 + z2 * cS2;
#pragma unroll
    for (int i = 0; i < 4; i++) {
#pragma unroll
        for (int j = 0; j < 4; j++) {
#pragma unroll
            for (int r = 0; r < 4; r++) {
                const int row = m0 + wm + i * 16 + quad * 4 + r;
                const int col = n0 + wn + j * 16 + r16;
                float v = acc[i][j][r];
                if (biasMode == 1)      v += bz[col];
                else if (biasMode == 2) v += bz[row];
                const size_t idx = (size_t)row * ldc + col;
                if (OUT_F16) Ch[idx] = (_Float16)v;
                else         Cf[idx] = v;
            }
        }
    }
}

// ---------------------------------------------------------------------------
// in-place fp16 softmax over rows of 512, scaled by 0.25 (head mean).
// one wave per row, vector 16B load/store per lane.
// ---------------------------------------------------------------------------
__global__ __launch_bounds__(256)
void softmax_f16(_Float16* __restrict__ S)
{
    const int row  = blockIdx.x * 4 + (threadIdx.x >> 6);
    const int lane = threadIdx.x & 63;
    _Float16* s = S + (size_t)row * 512 + lane * 8;
    half8 h = *(const half8*)s;
    float v[8];
    float mx = -1e30f;
#pragma unroll
    for (int j = 0; j < 8; j++) { v[j] = (float)h[j]; mx = fmaxf(mx, v[j]); }
#pragma unroll
    for (int off = 32; off; off >>= 1) mx = fmaxf(mx, __shfl_xor(mx, off));
    float sum = 0.f;
#pragma unroll
    for (int j = 0; j < 8; j++) { v[j] = __expf(v[j] - mx); sum += v[j]; }
#pragma unroll
    for (int off = 32; off; off >>= 1) sum += __shfl_xor(sum, off);
    const float inv = 0.25f / sum;
#pragma unroll
    for (int j = 0; j < 8; j++) h[j] = (_Float16)(v[j] * inv);
    *(half8*)s = h;
}

__global__ __launch_bounds__(256)
void cvt_f32_f16(const float* __restrict__ in, _Float16* __restrict__ out)
{
    const size_t i = ((size_t)blockIdx.x * blockDim.x + threadIdx.x) * 4;
    const float4 f = *(const float4*)(in + i);
    out[i + 0] = (_Float16)f.x;
    out[i + 1] = (_Float16)f.y;
    out[i + 2] = (_Float16)f.z;
    out[i + 3] = (_Float16)f.w;
}

// in [G][R][C] -> out [G][C][R], fp32 -> fp16. grid (C/32, R/32, G), block (32,8)
__global__ __launch_bounds__(256)
void transpose_cvt(const float* __restrict__ in, _Float16* __restrict__ out,
                   int R, int C)
{
    __shared__ float tile[32][33];
    const int g  = blockIdx.z;
    const int c0 = blockIdx.x * 32;
    const int r0 = blockIdx.y * 32;
    const float* inp  = in  + (size_t)g * R * C;
    _Float16*    outp = out + (size_t)g * R * C;
#pragma unroll
    for (int i = threadIdx.y; i < 32; i += 8)
        tile[i][threadIdx.x] = inp[(size_t)(r0 + i) * C + c0 + threadIdx.x];
    __syncthreads();
#pragma unroll
    for (int i = threadIdx.y; i < 32; i += 8)
        outp[(size_t)(c0 + i) * R + r0 + threadIdx.x] = (_Float16)tile[threadIdx.x][i];
}

// ---------------------------------------------------------------------------
extern "C" void kernel_launch(void* const* d_in, const int* in_sizes, int n_in,
                              void* d_out, int out_size, void* d_ws, size_t ws_size,
                              hipStream_t stream)
{
    (void)in_sizes; (void)n_in; (void)out_size;

    const float* x      = (const float*)d_in[0];
    const float* e_w0   = (const float*)d_in[1];
    const float* e_b0   = (const float*)d_in[2];
    const float* kq_w0  = (const float*)d_in[3];
    const float* kq_b0  = (const float*)d_in[4];
    const float* e_w1   = (const float*)d_in[5];
    const float* e_b1   = (const float*)d_in[6];
    const float* kq_w1  = (const float*)d_in[7];
    const float* kq_b1  = (const float*)d_in[8];
    const float* proj_w = (const float*)d_in[9];
    const float* proj_b = (const float*)d_in[10];
    float* out = (float*)d_out;

    // CHUNK=16 needs ~211 MB; fall back to 8 (~161 MB) if ws is tight.
    const int CH  = (ws_size >= (size_t)215 * 1024 * 1024) ? 16 : 8;
    const int NCH = B_ / CH;

    char* ws = (char*)d_ws;
    size_t off = 0;
    auto alloc = [&](size_t bytes) -> char* {
        char* p = ws + off;
        off += (bytes + 255) & ~(size_t)255;
        return p;
    };

    // h2 region doubles as x16 (x16 dead before h2 is written)
    char*     h2reg  = alloc((size_t)BN_ * DH_ * 2);                      // 33.5 MB
    _Float16* h2_16  = (_Float16*)h2reg;
    _Float16* x16    = (_Float16*)h2reg;   // BN_*DIN_*2 = 16.8 MB fits
    _Float16* h1_16  = (_Float16*)alloc((size_t)BN_ * DH_ * 2);           // 33.5 MB
    _Float16* ewT0   = (_Float16*)alloc((size_t)H_ * DH_ * DIN_ * 2);
    _Float16* kqwT0  = (_Float16*)alloc((size_t)H_ * 2 * DH_ * DIN_ * 2);
    _Float16* ewT1   = (_Float16*)alloc((size_t)H_ * DH_ * DH_ * 2);
    _Float16* kqwT1  = (_Float16*)alloc((size_t)H_ * 2 * DH_ * DH_ * 2);
    _Float16* projwT = (_Float16*)alloc((size_t)DOUT_ * DH_ * 2);
    _Float16* kqc    = (_Float16*)alloc((size_t)CH * N_ * H_ * 2 * DH_ * 2); // CH*4.2 MB
    _Float16* Sc     = (_Float16*)alloc((size_t)CH * H_ * N_ * N_ * 2);      // CH*2.1 MB
    _Float16* embTc  = (_Float16*)alloc((size_t)CH * H_ * DH_ * N_ * 2);     // CH*2.1 MB

    auto gemm = [&](bool outF16,
                    const _Float16* A, long long aS1, long long aS2, int lda, long long aSeg,
                    const _Float16* Bp, long long bS1, long long bS2, int ldb, long long bSeg,
                    void* C, long long cS1, long long cS2, int ldc,
                    int M, int Nn, int K, int batches, int zShift,
                    const float* bias, int biasMode, int biasS2) {
        dim3 grid(Nn / 128, M / 128, batches), block(256);
        if (outF16)
            gemm_f16<true><<<grid, block, 0, stream>>>(A, aS1, aS2, lda, aSeg,
                Bp, bS1, bS2, ldb, bSeg, C, cS1, cS2, ldc, K, bias, biasMode, biasS2, zShift);
        else
            gemm_f16<false><<<grid, block, 0, stream>>>(A, aS1, aS2, lda, aSeg,
                Bp, bS1, bS2, ldb, bSeg, C, cS1, cS2, ldc, K, bias, biasMode, biasS2, zShift);
    };

    // --- preprocessing -----------------------------------------------------
    cvt_f32_f16<<<BN_ * DIN_ / 1024, 256, 0, stream>>>(x, x16);
    transpose_cvt<<<dim3(DH_ / 32, DIN_ / 32, H_), dim3(32, 8), 0, stream>>>(e_w0, ewT0, DIN_, DH_);
    transpose_cvt<<<dim3(2 * DH_ / 32, DIN_ / 32, H_), dim3(32, 8), 0, stream>>>(kq_w0, kqwT0, DIN_, 2 * DH_);
    transpose_cvt<<<dim3(DH_ / 32, DH_ / 32, H_), dim3(32, 8), 0, stream>>>(e_w1, ewT1, DH_, DH_);
    transpose_cvt<<<dim3(2 * DH_ / 32, DH_ / 32, H_), dim3(32, 8), 0, stream>>>(kq_w1, kqwT1, DH_, 2 * DH_);
    transpose_cvt<<<dim3(DOUT_ / 32, DH_ / 32, 1), dim3(32, 8), 0, stream>>>(proj_w, projwT, DH_, DOUT_);

    const long long QK = (long long)N_ * H_ * 2 * DH_;   // kqc row-block per b
    const long long SB = (long long)N_ * N_;             // one S matrix

    // --- two attention blocks ---------------------------------------------
    for (int blk = 0; blk < 2; blk++) {
        const _Float16* xin  = blk ? h1_16 : x16;
        const int       Kin  = blk ? DH_ : DIN_;
        const _Float16* ewT  = blk ? ewT1 : ewT0;
        const _Float16* kqwT = blk ? kqwT1 : kqwT0;
        const float*    eb   = blk ? e_b1 : e_b0;
        const float*    kqb  = blk ? kq_b1 : kq_b0;
        _Float16*       hout = blk ? h2_16 : h1_16;

        for (int c = 0; c < NCH; c++) {
            const _Float16* xc = xin  + (size_t)c * CH * N_ * Kin;
            _Float16*       hc = hout + (size_t)c * CH * N_ * DH_;

            // kq (all heads): [CH*N, H*2DH] = xc @ kqwT^T + kqb
            gemm(true, xc, 0, 0, Kin, 512,
                 kqwT, 0, 0, Kin, 512,
                 kqc, 0, 0, H_ * 2 * DH_,
                 CH * N_, H_ * 2 * DH_, Kin, 1, 0, kqb, 1, 0);
            // embT[b][h][e][n] = ewT[h] @ xc[b]^T + eb[h][e]
            gemm(true, ewT, 0, (long long)DH_ * Kin, Kin, 512,
                 xc, (long long)N_ * Kin, 0, Kin, 512,
                 embTc, (long long)H_ * DH_ * N_, (long long)DH_ * N_, N_,
                 DH_, N_, Kin, CH * H_, 2, eb, 2, DH_);
            // S[b][h][q][k] = Q K^T (fp16)
            gemm(true, kqc + DH_, QK, 2 * DH_, 2 * H_ * DH_, 512,
                 kqc,        QK, 2 * DH_, 2 * H_ * DH_, 512,
                 Sc, (long long)H_ * SB, SB, N_,
                 N_, N_, DH_, CH * H_, 2, nullptr, 0, 0);
            // P = softmax(S) * 0.25 (in place, fp16)
            softmax_f16<<<CH * H_ * N_ / 4, 256, 0, stream>>>(Sc);
            // h[b][q][e] = sum over h of P_h @ embT_h^T  (segmented K=2048)
            gemm(true, Sc, (long long)H_ * SB, 0, N_, SB,
                 embTc, (long long)H_ * DH_ * N_, 0, N_, (long long)DH_ * N_,
                 hc, (long long)N_ * DH_, 0, DH_,
                 N_, DH_, H_ * N_, CH, 0, nullptr, 0, 0);
        }
    }

    // --- output projection -------------------------------------------------
    gemm(false, h2_16, 0, 0, DH_, 512,
         projwT, 0, 0, DH_, 512,
         out, 0, 0, DOUT_,
         BN_, DOUT_, DH_, 1, 0, proj_b, 1, 0);
}

// Round 4
// 1228.813 us; speedup vs baseline: 1.8859x; 1.5235x over previous
//
#include <hip/hip_runtime.h>

typedef _Float16 half8 __attribute__((ext_vector_type(8)));
typedef float floatx4 __attribute__((ext_vector_type(4)));

#define B_    64
#define N_    512
#define DIN_  256
#define DH_   512
#define DOUT_ 256
#define H_    4
#define BN_   (B_ * N_)   // 32768

// raw waitcnt immediates (gfx9: vmcnt[3:0]|[15:14], exp[6:4], lgkm[11:8])
#define WAIT_VM4()   __builtin_amdgcn_s_waitcnt(0x0F74)
#define WAIT_VM0()   __builtin_amdgcn_s_waitcnt(0x0F70)
#define WAIT_LGKM0() __builtin_amdgcn_s_waitcnt(0xC07F)
#define MEMBAR()     __asm__ __volatile__("" ::: "memory")

__device__ static inline void async_copy16(const _Float16* g, _Float16* l) {
    __builtin_amdgcn_global_load_lds(
        (const __attribute__((address_space(1))) void*)g,
        (__attribute__((address_space(3))) void*)l, 16, 0, 0);
}

// ---------------------------------------------------------------------------
// GEMM: C[M,N] = A[M,K] * B[N,K]^T (+bias). fp16 in, fp16/fp32 out.
// Segmented K (512-elem segments): A elem (row,k) at z1*aS1 + z2*aS2
//   + row*lda + (k>>9)*aSeg + (k&511).  z1 = z>>zShift, z2 = z&mask.
// Tile 128x128, BK=32, 4 waves, 4x4 MFMA 16x16x32 f16. Double-buffered LDS,
// raw vmcnt(4) pipeline. biasMode: 0 none, 1 bias[col], 2 bias[row];
// bias += z1*biasS1 + z2*biasS2.
// ---------------------------------------------------------------------------
template <bool OUT_F16>
__global__ __launch_bounds__(256)
void gemm_f16(const _Float16* __restrict__ A, long long aS1, long long aS2, int lda, long long aSeg,
              const _Float16* __restrict__ B, long long bS1, long long bS2, int ldb, long long bSeg,
              void* __restrict__ Cv, long long cS1, long long cS2, int ldc,
              int K, const float* __restrict__ bias, int biasMode,
              long long biasS1, long long biasS2, int zShift)
{
    __shared__ __align__(16) _Float16 As[2][128 * 32];
    __shared__ __align__(16) _Float16 Bs[2][128 * 32];

    const int tid  = threadIdx.x;
    const int wave = tid >> 6;
    const int lane = tid & 63;
    const int quad = lane >> 4;
    const int r16  = lane & 15;

    const int z  = blockIdx.z;
    const int z1 = z >> zShift;
    const int z2 = z & ((1 << zShift) - 1);

    const int gx = gridDim.x, gy = gridDim.y;
    const int T = gx * gy;
    int lin = blockIdx.y * gx + blockIdx.x;
    int id2 = (T & 7) ? lin : ((lin & 7) * (T >> 3) + (lin >> 3));
    const int m0 = (id2 / gx) * 128;
    const int n0 = (id2 % gx) * 128;

    const int srow = lane >> 2;        // 0..15
    const int scol = (lane & 3) * 8;   // k offset within tile

    const _Float16* gaRow = A + z1 * aS1 + z2 * aS2
                              + (long long)(m0 + wave * 32 + srow) * lda + scol;
    const _Float16* gbRow = B + z1 * bS1 + z2 * bS2
                              + (long long)(n0 + wave * 32 + srow) * ldb + scol;

    const int wm = (wave >> 1) * 64;
    const int wn = (wave & 1) * 64;

    floatx4 acc[4][4];
#pragma unroll
    for (int i = 0; i < 4; i++)
#pragma unroll
        for (int j = 0; j < 4; j++) acc[i][j] = (floatx4){0.f, 0.f, 0.f, 0.f};

    auto stage = [&](int p, int k0) {
        const _Float16* a = gaRow + (long long)(k0 >> 9) * aSeg + (k0 & 511);
        const _Float16* b = gbRow + (long long)(k0 >> 9) * bSeg + (k0 & 511);
        _Float16* la = &As[p][wave * 1024];
        _Float16* lb = &Bs[p][wave * 1024];
        async_copy16(a,                    la);
        async_copy16(a + (size_t)16 * lda, la + 512);
        async_copy16(b,                    lb);
        async_copy16(b + (size_t)16 * ldb, lb + 512);
    };

    auto compute = [&](int p) {
        half8 af[4], bf[4];
#pragma unroll
        for (int i = 0; i < 4; i++)
            af[i] = *(const half8*)&As[p][(wm + i * 16 + r16) * 32 + quad * 8];
#pragma unroll
        for (int j = 0; j < 4; j++)
            bf[j] = *(const half8*)&Bs[p][(wn + j * 16 + r16) * 32 + quad * 8];
#pragma unroll
        for (int i = 0; i < 4; i++)
#pragma unroll
            for (int j = 0; j < 4; j++)
                acc[i][j] = __builtin_amdgcn_mfma_f32_16x16x32_f16(
                    af[i], bf[j], acc[i][j], 0, 0, 0);
    };

    const int niter = K >> 5;
    stage(0, 0);
    for (int it = 0; it < niter - 1; ++it) {
        stage((it + 1) & 1, (it + 1) << 5);
        MEMBAR(); WAIT_VM4();
        __builtin_amdgcn_s_barrier(); MEMBAR();
        compute(it & 1);
        MEMBAR(); WAIT_LGKM0();
        __builtin_amdgcn_s_barrier(); MEMBAR();
    }
    MEMBAR(); WAIT_VM0();
    __builtin_amdgcn_s_barrier(); MEMBAR();
    compute((niter - 1) & 1);

    // epilogue: C/D layout col = lane&15, row = quad*4 + reg
    const float* bz = bias + z1 * biasS1 + z2 * biasS2;
    float*    Cf = (float*)Cv    + z1 * cS1 + z2 * cS2;
    _Float16* Ch = (_Float16*)Cv + z1 * cS1 + z2 * cS2;
#pragma unroll
    for (int i = 0; i < 4; i++) {
#pragma unroll
        for (int j = 0; j < 4; j++) {
#pragma unroll
            for (int r = 0; r < 4; r++) {
                const int row = m0 + wm + i * 16 + quad * 4 + r;
                const int col = n0 + wn + j * 16 + r16;
                float v = acc[i][j][r];
                if (biasMode == 1)      v += bz[col];
                else if (biasMode == 2) v += bz[row];
                const size_t idx = (size_t)row * ldc + col;
                if (OUT_F16) Ch[idx] = (_Float16)v;
                else         Cf[idx] = v;
            }
        }
    }
}

// ---------------------------------------------------------------------------
// in-place fp16 softmax over rows of 512, scaled by 0.25 (head mean).
// ---------------------------------------------------------------------------
__global__ __launch_bounds__(256)
void softmax_f16(_Float16* __restrict__ S)
{
    const int row  = blockIdx.x * 4 + (threadIdx.x >> 6);
    const int lane = threadIdx.x & 63;
    _Float16* s = S + (size_t)row * 512 + lane * 8;
    half8 h = *(const half8*)s;
    float v[8];
    float mx = -1e30f;
#pragma unroll
    for (int j = 0; j < 8; j++) { v[j] = (float)h[j]; mx = fmaxf(mx, v[j]); }
#pragma unroll
    for (int off = 32; off; off >>= 1) mx = fmaxf(mx, __shfl_xor(mx, off));
    float sum = 0.f;
#pragma unroll
    for (int j = 0; j < 8; j++) { v[j] = __expf(v[j] - mx); sum += v[j]; }
#pragma unroll
    for (int off = 32; off; off >>= 1) sum += __shfl_xor(sum, off);
    const float inv = 0.25f / sum;
#pragma unroll
    for (int j = 0; j < 8; j++) h[j] = (_Float16)(v[j] * inv);
    *(half8*)s = h;
}

__global__ __launch_bounds__(256)
void cvt_f32_f16(const float* __restrict__ in, _Float16* __restrict__ out)
{
    const size_t i = ((size_t)blockIdx.x * blockDim.x + threadIdx.x) * 4;
    const float4 f = *(const float4*)(in + i);
    out[i + 0] = (_Float16)f.x;
    out[i + 1] = (_Float16)f.y;
    out[i + 2] = (_Float16)f.z;
    out[i + 3] = (_Float16)f.w;
}

// in [G][R][C] -> out [G][C][R], fp32 -> fp16
__global__ __launch_bounds__(256)
void transpose_cvt(const float* __restrict__ in, _Float16* __restrict__ out,
                   int R, int C)
{
    __shared__ float tile[32][33];
    const int g  = blockIdx.z;
    const int c0 = blockIdx.x * 32;
    const int r0 = blockIdx.y * 32;
    const float* inp  = in  + (size_t)g * R * C;
    _Float16*    outp = out + (size_t)g * R * C;
#pragma unroll
    for (int i = threadIdx.y; i < 32; i += 8)
        tile[i][threadIdx.x] = inp[(size_t)(r0 + i) * C + c0 + threadIdx.x];
    __syncthreads();
#pragma unroll
    for (int i = threadIdx.y; i < 32; i += 8)
        outp[(size_t)(c0 + i) * R + r0 + threadIdx.x] = (_Float16)tile[threadIdx.x][i];
}

// w[h][d] = sum_e kq_w[h][d][DH+... : Wk[d,e] * bq[e]   (Wk = cols 0..DH-1,
// bq = kq_b[h][DH..2DH-1]).  one thread per (h,d); dinShift = log2(DINb)
__global__ __launch_bounds__(256)
void wk_bq(const float* __restrict__ kq_w, const float* __restrict__ kq_b,
           float* __restrict__ w, int dinShift)
{
    const int t = blockIdx.x * 256 + threadIdx.x;
    const int h = t >> dinShift;
    const int d = t & ((1 << dinShift) - 1);
    const float* wk = kq_w + ((size_t)(h << dinShift) + d) * (2 * DH_);
    const float* bq = kq_b + (size_t)h * 2 * DH_ + DH_;
    float s = 0.f;
    for (int e = 0; e < DH_; e++) s += wk[e] * bq[e];
    w[t] = s;
}

// be1p[h][o] = sum_d e_b1[h][d] * projwT[o][d]
__global__ __launch_bounds__(256)
void fold_bias(const _Float16* __restrict__ projwT, const float* __restrict__ e_b1,
               float* __restrict__ be1p)
{
    const int t = blockIdx.x * 256 + threadIdx.x;   // t < H*DOUT
    const int h = t >> 8;
    const int o = t & 255;
    const _Float16* pw = projwT + (size_t)o * DH_;
    const float*    eb = e_b1 + (size_t)h * DH_;
    float s = 0.f;
    for (int d = 0; d < DH_; d++) s += (float)pw[d] * eb[d];
    be1p[t] = s;
}

// V[b][h][n] = x[b*N+n, :] . w[h, :]   — one wave per row, 4 heads at once
__global__ __launch_bounds__(256)
void compute_v(const _Float16* __restrict__ x, const float* __restrict__ w,
               float* __restrict__ V, int Kin)
{
    const int row  = blockIdx.x * 4 + (threadIdx.x >> 6);
    const int lane = threadIdx.x & 63;
    const int b = row >> 9, n = row & 511;
    const _Float16* xr = x + (size_t)row * Kin;
    float s0 = 0.f, s1 = 0.f, s2 = 0.f, s3 = 0.f;
    const int iters = Kin >> 6;
    for (int j = 0; j < iters; j++) {
        const int idx = lane + j * 64;
        const float xv = (float)xr[idx];
        s0 += xv * w[idx];
        s1 += xv * w[Kin + idx];
        s2 += xv * w[2 * Kin + idx];
        s3 += xv * w[3 * Kin + idx];
    }
#pragma unroll
    for (int off = 32; off; off >>= 1) {
        s0 += __shfl_xor(s0, off); s1 += __shfl_xor(s1, off);
        s2 += __shfl_xor(s2, off); s3 += __shfl_xor(s3, off);
    }
    if (lane == 0) {
        float* vb = V + ((size_t)b * H_) * N_ + n;
        vb[0] = s0; vb[N_] = s1; vb[2 * N_] = s2; vb[3 * N_] = s3;
    }
}

// ---------------------------------------------------------------------------
extern "C" void kernel_launch(void* const* d_in, const int* in_sizes, int n_in,
                              void* d_out, int out_size, void* d_ws, size_t ws_size,
                              hipStream_t stream)
{
    (void)in_sizes; (void)n_in; (void)out_size;

    const float* x      = (const float*)d_in[0];
    const float* e_w0   = (const float*)d_in[1];
    const float* e_b0   = (const float*)d_in[2];
    const float* kq_w0  = (const float*)d_in[3];
    const float* kq_b0  = (const float*)d_in[4];
    const float* e_w1   = (const float*)d_in[5];
    const float* e_b1   = (const float*)d_in[6];
    const float* kq_w1  = (const float*)d_in[7];
    const float* kq_b1  = (const float*)d_in[8];
    const float* proj_w = (const float*)d_in[9];
    const float* proj_b = (const float*)d_in[10];
    float* out = (float*)d_out;

    char* ws = (char*)d_ws;
    size_t off = 0;
    auto alloc = [&](size_t bytes) -> char* {
        char* p = ws + off;
        off += (bytes + 255) & ~(size_t)255;
        return p;
    };

    // persistent (~64 MB)
    _Float16* x16    = (_Float16*)alloc((size_t)BN_ * DIN_ * 2);          // 16.8 MB
    _Float16* h1_16  = (_Float16*)alloc((size_t)BN_ * DH_ * 2);           // 33.5 MB
    _Float16* kq0_16 = (_Float16*)alloc((size_t)H_ * DIN_ * 2 * DH_ * 2); //  2.1 MB
    _Float16* kq1_16 = (_Float16*)alloc((size_t)H_ * DH_ * 2 * DH_ * 2);  //  4.2 MB
    _Float16* ew1_16 = (_Float16*)alloc((size_t)H_ * DH_ * DH_ * 2);      //  2.1 MB
    _Float16* ewT0   = (_Float16*)alloc((size_t)H_ * DH_ * DIN_ * 2);     //  1.0 MB
    _Float16* projwT = (_Float16*)alloc((size_t)DOUT_ * DH_ * 2);         //  0.3 MB
    _Float16* Mt0    = (_Float16*)alloc((size_t)H_ * DIN_ * DIN_ * 2);    //  0.5 MB
    _Float16* Mt1    = (_Float16*)alloc((size_t)H_ * DH_ * DH_ * 2);      //  2.1 MB
    _Float16* We1pT  = (_Float16*)alloc((size_t)H_ * DOUT_ * DH_ * 2);    //  1.0 MB
    float*    be1p   = (float*)alloc((size_t)H_ * DOUT_ * 4);
    float*    w0     = (float*)alloc((size_t)H_ * DIN_ * 4);
    float*    w1     = (float*)alloc((size_t)H_ * DH_ * 4);
    float*    Vb     = (float*)alloc((size_t)B_ * H_ * N_ * 4);           //  0.5 MB

    // chunk buffers: pick CH by available ws
    const size_t persist = off;
    auto chunkBytes = [](int ch) {
        return (size_t)ch * N_ * H_ * DH_ * 2       // T
             + (size_t)ch * H_ * N_ * N_ * 2        // Sc
             + (size_t)ch * H_ * DH_ * N_ * 2;      // embc (block0 worst)
    };
    int CH = 8;
    if (ws_size >= persist + chunkBytes(32) + (1u << 20)) CH = 32;
    else if (ws_size >= persist + chunkBytes(16) + (1u << 20)) CH = 16;
    const int NCH = B_ / CH;

    _Float16* Tc   = (_Float16*)alloc((size_t)CH * N_ * H_ * DH_ * 2);
    _Float16* Sc   = (_Float16*)alloc((size_t)CH * H_ * N_ * N_ * 2);
    _Float16* embc = (_Float16*)alloc((size_t)CH * H_ * DH_ * N_ * 2);

    auto gemm = [&](bool outF16,
                    const _Float16* A, long long aS1, long long aS2, int lda, long long aSeg,
                    const _Float16* Bp, long long bS1, long long bS2, int ldb, long long bSeg,
                    void* C, long long cS1, long long cS2, int ldc,
                    int M, int Nn, int K, int batches, int zShift,
                    const float* bias, int biasMode, long long biasS1, long long biasS2) {
        dim3 grid(Nn / 128, M / 128, batches), block(256);
        if (outF16)
            gemm_f16<true><<<grid, block, 0, stream>>>(A, aS1, aS2, lda, aSeg,
                Bp, bS1, bS2, ldb, bSeg, C, cS1, cS2, ldc, K, bias, biasMode, biasS1, biasS2, zShift);
        else
            gemm_f16<false><<<grid, block, 0, stream>>>(A, aS1, aS2, lda, aSeg,
                Bp, bS1, bS2, ldb, bSeg, C, cS1, cS2, ldc, K, bias, biasMode, biasS1, biasS2, zShift);
    };

    // --- preprocessing -----------------------------------------------------
    cvt_f32_f16<<<BN_ * DIN_ / 1024, 256, 0, stream>>>(x, x16);
    cvt_f32_f16<<<H_ * DIN_ * 2 * DH_ / 1024, 256, 0, stream>>>(kq_w0, kq0_16);
    cvt_f32_f16<<<H_ * DH_ * 2 * DH_ / 1024, 256, 0, stream>>>(kq_w1, kq1_16);
    cvt_f32_f16<<<H_ * DH_ * DH_ / 1024, 256, 0, stream>>>(e_w1, ew1_16);
    transpose_cvt<<<dim3(DH_ / 32, DIN_ / 32, H_), dim3(32, 8), 0, stream>>>(e_w0, ewT0, DIN_, DH_);
    transpose_cvt<<<dim3(DOUT_ / 32, DH_ / 32, 1), dim3(32, 8), 0, stream>>>(proj_w, projwT, DH_, DOUT_);

    // Mt_h = Wk_h * Wq_h^T  (so T = x * Mt^T = x * (Wq Wk^T))
    gemm(true, kq0_16, 0, (long long)DIN_ * 2 * DH_, 2 * DH_, 512,
         kq0_16 + DH_, 0, (long long)DIN_ * 2 * DH_, 2 * DH_, 512,
         Mt0, 0, (long long)DIN_ * DIN_, DIN_,
         DIN_, DIN_, DH_, H_, 2, nullptr, 0, 0, 0);
    gemm(true, kq1_16, 0, (long long)DH_ * 2 * DH_, 2 * DH_, 512,
         kq1_16 + DH_, 0, (long long)DH_ * 2 * DH_, 2 * DH_, 512,
         Mt1, 0, (long long)DH_ * DH_, DH_,
         DH_, DH_, DH_, H_, 2, nullptr, 0, 0, 0);
    // We1pT[h][o][d] = sum_d' projwT[o][d'] * e_w1[h][d][d']
    gemm(true, projwT, 0, 0, DH_, 512,
         ew1_16, 0, (long long)DH_ * DH_, DH_, 512,
         We1pT, 0, (long long)DOUT_ * DH_, DH_,
         DOUT_, DH_, DH_, H_, 2, nullptr, 0, 0, 0);
    fold_bias<<<H_ * DOUT_ / 256, 256, 0, stream>>>(projwT, e_b1, be1p);
    wk_bq<<<H_ * DIN_ / 256, 256, 0, stream>>>(kq_w0, kq_b0, w0, 8);
    wk_bq<<<H_ * DH_ / 256, 256, 0, stream>>>(kq_w1, kq_b1, w1, 9);

    const long long SB = (long long)N_ * N_;

    // --- two attention blocks ---------------------------------------------
    for (int blk = 0; blk < 2; blk++) {
        const _Float16* xin = blk ? h1_16 : x16;
        const int       Kin = blk ? DH_ : DIN_;
        const _Float16* Mt  = blk ? Mt1 : Mt0;
        const float*    wv  = blk ? w1 : w0;

        // V[b][h][n] for the whole batch (input to this block fully ready)
        compute_v<<<BN_ / 4, 256, 0, stream>>>(xin, wv, Vb, Kin);

        for (int c = 0; c < NCH; c++) {
            const _Float16* xc = xin + (size_t)c * CH * N_ * Kin;

            // T[q, h*Kin+d'] = sum_d x[q,d] * Mt[h*Kin+d', d]
            gemm(true, xc, 0, 0, Kin, 512,
                 Mt, 0, 0, Kin, 512,
                 Tc, 0, 0, H_ * Kin,
                 CH * N_, H_ * Kin, Kin, 1, 0, nullptr, 0, 0, 0);
            // S[b][h][q][k] = T[b,h] * x_b^T + V[b][h][k]
            gemm(true, Tc, (long long)N_ * H_ * Kin, Kin, H_ * Kin, 512,
                 xc, (long long)N_ * Kin, 0, Kin, 512,
                 Sc, (long long)H_ * SB, SB, N_,
                 N_, N_, Kin, CH * H_, 2,
                 Vb + (size_t)c * CH * H_ * N_, 1, (long long)H_ * N_, N_);
            // P = softmax(S) * 0.25, in place fp16
            softmax_f16<<<CH * H_ * N_ / 4, 256, 0, stream>>>(Sc);

            if (blk == 0) {
                // embT[b][h*DH+e][n] = ewT0 @ x_b^T + e_b0
                gemm(true, ewT0, 0, 0, Kin, 512,
                     xc, (long long)N_ * Kin, 0, Kin, 512,
                     embc, (long long)H_ * DH_ * N_, 0, N_,
                     H_ * DH_, N_, Kin, CH, 0, e_b0, 2, 0, 0);
                // h1[b][q][e] = sum_{h,n} P * embT   (segmented K = H*N)
                gemm(true, Sc, (long long)H_ * SB, 0, N_, SB,
                     embc, (long long)H_ * DH_ * N_, 0, N_, (long long)DH_ * N_,
                     h1_16 + (size_t)c * CH * N_ * DH_, (long long)N_ * DH_, 0, DH_,
                     N_, DH_, H_ * N_, CH, 0, nullptr, 0, 0, 0);
            } else {
                // embWT[b][h*DOUT+o][n] = We1pT @ h1_b^T + be1p
                gemm(true, We1pT, 0, 0, DH_, 512,
                     xc, (long long)N_ * DH_, 0, DH_, 512,
                     embc, (long long)H_ * DOUT_ * N_, 0, N_,
                     H_ * DOUT_, N_, DH_, CH, 0, be1p, 2, 0, 0);
                // out[b][q][o] = sum_{h,n} P * embWT + proj_b  (fp32)
                gemm(false, Sc, (long long)H_ * SB, 0, N_, SB,
                     embc, (long long)H_ * DOUT_ * N_, 0, N_, (long long)DOUT_ * N_,
                     out + (size_t)c * CH * N_ * DOUT_, (long long)N_ * DOUT_, 0, DOUT_,
                     N_, DOUT_, H_ * N_, CH, 0, proj_b, 1, 0, 0);
            }
        }
    }
}

// Round 5
// 1215.250 us; speedup vs baseline: 1.9070x; 1.0112x over previous
//
#include <hip/hip_runtime.h>

typedef _Float16 half8 __attribute__((ext_vector_type(8)));
typedef float floatx4 __attribute__((ext_vector_type(4)));

#define B_    64
#define N_    512
#define DIN_  256
#define DH_   512
#define DOUT_ 256
#define H_    4
#define BN_   (B_ * N_)   // 32768

// raw waitcnt immediates (gfx9: vmcnt[3:0]|[15:14], exp[6:4], lgkm[11:8])
#define WAIT_VM4_LGKM0() __builtin_amdgcn_s_waitcnt(0x0074)  // vm<=4, lgkm<=0
#define WAIT_VM0_LGKM0() __builtin_amdgcn_s_waitcnt(0x0070)  // vm<=0, lgkm<=0
#define MEMBAR()         __asm__ __volatile__("" ::: "memory")

__device__ static inline void async_copy16(const _Float16* g, _Float16* l) {
    __builtin_amdgcn_global_load_lds(
        (const __attribute__((address_space(1))) void*)g,
        (__attribute__((address_space(3))) void*)l, 16, 0, 0);
}

// ---------------------------------------------------------------------------
// GEMM: C[M,N] = A[M,K] * B[N,K]^T (+bias). fp16 in, fp16/fp32 out.
// Segmented K (512-elem segments): A elem (row,k) at z1*aS1 + z2*aS2
//   + row*lda + (k>>9)*aSeg + (k&511).  z1 = z>>zShift, z2 = z&mask.
// Tile 128x128, BK=32, 4 waves, 4x4 MFMA 16x16x32 f16.
// TRIPLE-buffered LDS, 2-iter-deep async prefetch (covers ~900cyc HBM
// latency), ONE barrier per iter:  wait(vm4,lgkm0); barrier; stage(it+2);
// compute(it).  Writes to buf (it+2)%3 are safe: its readers (iter it-1)
// drained lgkm before this barrier.
// biasMode: 0 none, 1 bias[col], 2 bias[row]; bias += z1*biasS1 + z2*biasS2.
// ---------------------------------------------------------------------------
template <bool OUT_F16>
__global__ __launch_bounds__(256)
void gemm_f16(const _Float16* __restrict__ A, long long aS1, long long aS2, int lda, long long aSeg,
              const _Float16* __restrict__ B, long long bS1, long long bS2, int ldb, long long bSeg,
              void* __restrict__ Cv, long long cS1, long long cS2, int ldc,
              int K, const float* __restrict__ bias, int biasMode,
              long long biasS1, long long biasS2, int zShift)
{
    __shared__ __align__(16) _Float16 As[3][128 * 32];
    __shared__ __align__(16) _Float16 Bs[3][128 * 32];

    const int tid  = threadIdx.x;
    const int wave = tid >> 6;
    const int lane = tid & 63;
    const int quad = lane >> 4;
    const int r16  = lane & 15;

    const int z  = blockIdx.z;
    const int z1 = z >> zShift;
    const int z2 = z & ((1 << zShift) - 1);

    const int gx = gridDim.x, gy = gridDim.y;
    const int T = gx * gy;
    int lin = blockIdx.y * gx + blockIdx.x;
    int id2 = (T & 7) ? lin : ((lin & 7) * (T >> 3) + (lin >> 3));
    const int m0 = (id2 / gx) * 128;
    const int n0 = (id2 % gx) * 128;

    const int srow = lane >> 2;        // 0..15
    const int scol = (lane & 3) * 8;   // k offset within tile

    const _Float16* gaRow = A + z1 * aS1 + z2 * aS2
                              + (long long)(m0 + wave * 32 + srow) * lda + scol;
    const _Float16* gbRow = B + z1 * bS1 + z2 * bS2
                              + (long long)(n0 + wave * 32 + srow) * ldb + scol;

    const int wm = (wave >> 1) * 64;
    const int wn = (wave & 1) * 64;

    floatx4 acc[4][4];
#pragma unroll
    for (int i = 0; i < 4; i++)
#pragma unroll
        for (int j = 0; j < 4; j++) acc[i][j] = (floatx4){0.f, 0.f, 0.f, 0.f};

    auto stage = [&](int p, int k0) {
        const _Float16* a = gaRow + (long long)(k0 >> 9) * aSeg + (k0 & 511);
        const _Float16* b = gbRow + (long long)(k0 >> 9) * bSeg + (k0 & 511);
        _Float16* la = &As[p][wave * 1024];
        _Float16* lb = &Bs[p][wave * 1024];
        async_copy16(a,                    la);
        async_copy16(a + (size_t)16 * lda, la + 512);
        async_copy16(b,                    lb);
        async_copy16(b + (size_t)16 * ldb, lb + 512);
    };

    auto compute = [&](int p) {
        half8 af[4], bf[4];
#pragma unroll
        for (int i = 0; i < 4; i++)
            af[i] = *(const half8*)&As[p][(wm + i * 16 + r16) * 32 + quad * 8];
#pragma unroll
        for (int j = 0; j < 4; j++)
            bf[j] = *(const half8*)&Bs[p][(wn + j * 16 + r16) * 32 + quad * 8];
#pragma unroll
        for (int i = 0; i < 4; i++)
#pragma unroll
            for (int j = 0; j < 4; j++)
                acc[i][j] = __builtin_amdgcn_mfma_f32_16x16x32_f16(
                    af[i], bf[j], acc[i][j], 0, 0, 0);
    };

    const int niter = K >> 5;           // >= 8 for all shapes here
    stage(0, 0);
    stage(1, 32);
    int pNext = 2;                       // buffer to stage (it+2)
    int pCur  = 0;                       // buffer to compute (it)
    for (int it = 0; it < niter - 1; ++it) {
        MEMBAR(); WAIT_VM4_LGKM0();      // oldest 4 loads (buf pCur) landed;
        __builtin_amdgcn_s_barrier();    // all waves' LDS reads of pNext done
        MEMBAR();
        if (it + 2 < niter) stage(pNext, (it + 2) << 5);
        compute(pCur);
        MEMBAR();
        pNext = (pNext == 2) ? 0 : pNext + 1;
        pCur  = (pCur  == 2) ? 0 : pCur  + 1;
    }
    MEMBAR(); WAIT_VM0_LGKM0();
    __builtin_amdgcn_s_barrier(); MEMBAR();
    compute(pCur);

    // epilogue: C/D layout col = lane&15, row = quad*4 + reg
    const float* bz = bias + z1 * biasS1 + z2 * biasS2;
    float*    Cf = (float*)Cv    + z1 * cS1 + z2 * cS2;
    _Float16* Ch = (_Float16*)Cv + z1 * cS1 + z2 * cS2;
#pragma unroll
    for (int i = 0; i < 4; i++) {
#pragma unroll
        for (int j = 0; j < 4; j++) {
#pragma unroll
            for (int r = 0; r < 4; r++) {
                const int row = m0 + wm + i * 16 + quad * 4 + r;
                const int col = n0 + wn + j * 16 + r16;
                float v = acc[i][j][r];
                if (biasMode == 1)      v += bz[col];
                else if (biasMode == 2) v += bz[row];
                const size_t idx = (size_t)row * ldc + col;
                if (OUT_F16) Ch[idx] = (_Float16)v;
                else         Cf[idx] = v;
            }
        }
    }
}

// ---------------------------------------------------------------------------
// in-place fp16 softmax over rows of 512, scaled by 0.25 (head mean).
// ---------------------------------------------------------------------------
__global__ __launch_bounds__(256)
void softmax_f16(_Float16* __restrict__ S)
{
    const int row  = blockIdx.x * 4 + (threadIdx.x >> 6);
    const int lane = threadIdx.x & 63;
    _Float16* s = S + (size_t)row * 512 + lane * 8;
    half8 h = *(const half8*)s;
    float v[8];
    float mx = -1e30f;
#pragma unroll
    for (int j = 0; j < 8; j++) { v[j] = (float)h[j]; mx = fmaxf(mx, v[j]); }
#pragma unroll
    for (int off = 32; off; off >>= 1) mx = fmaxf(mx, __shfl_xor(mx, off));
    float sum = 0.f;
#pragma unroll
    for (int j = 0; j < 8; j++) { v[j] = __expf(v[j] - mx); sum += v[j]; }
#pragma unroll
    for (int off = 32; off; off >>= 1) sum += __shfl_xor(sum, off);
    const float inv = 0.25f / sum;
#pragma unroll
    for (int j = 0; j < 8; j++) h[j] = (_Float16)(v[j] * inv);
    *(half8*)s = h;
}

__global__ __launch_bounds__(256)
void cvt_f32_f16(const float* __restrict__ in, _Float16* __restrict__ out)
{
    const size_t i = ((size_t)blockIdx.x * blockDim.x + threadIdx.x) * 4;
    const float4 f = *(const float4*)(in + i);
    out[i + 0] = (_Float16)f.x;
    out[i + 1] = (_Float16)f.y;
    out[i + 2] = (_Float16)f.z;
    out[i + 3] = (_Float16)f.w;
}

// in [G][R][C] -> out [G][C][R], fp32 -> fp16
__global__ __launch_bounds__(256)
void transpose_cvt(const float* __restrict__ in, _Float16* __restrict__ out,
                   int R, int C)
{
    __shared__ float tile[32][33];
    const int g  = blockIdx.z;
    const int c0 = blockIdx.x * 32;
    const int r0 = blockIdx.y * 32;
    const float* inp  = in  + (size_t)g * R * C;
    _Float16*    outp = out + (size_t)g * R * C;
#pragma unroll
    for (int i = threadIdx.y; i < 32; i += 8)
        tile[i][threadIdx.x] = inp[(size_t)(r0 + i) * C + c0 + threadIdx.x];
    __syncthreads();
#pragma unroll
    for (int i = threadIdx.y; i < 32; i += 8)
        outp[(size_t)(c0 + i) * R + r0 + threadIdx.x] = (_Float16)tile[threadIdx.x][i];
}

// w[h][d] = sum_e Wk[h][d][e] * bq[h][e]
__global__ __launch_bounds__(256)
void wk_bq(const float* __restrict__ kq_w, const float* __restrict__ kq_b,
           float* __restrict__ w, int dinShift)
{
    const int t = blockIdx.x * 256 + threadIdx.x;
    const int h = t >> dinShift;
    const int d = t & ((1 << dinShift) - 1);
    const float* wk = kq_w + ((size_t)(h << dinShift) + d) * (2 * DH_);
    const float* bq = kq_b + (size_t)h * 2 * DH_ + DH_;
    float s = 0.f;
    for (int e = 0; e < DH_; e++) s += wk[e] * bq[e];
    w[t] = s;
}

// be1p[h][o] = sum_d e_b1[h][d] * projwT[o][d]
__global__ __launch_bounds__(256)
void fold_bias(const _Float16* __restrict__ projwT, const float* __restrict__ e_b1,
               float* __restrict__ be1p)
{
    const int t = blockIdx.x * 256 + threadIdx.x;   // t < H*DOUT
    const int h = t >> 8;
    const int o = t & 255;
    const _Float16* pw = projwT + (size_t)o * DH_;
    const float*    eb = e_b1 + (size_t)h * DH_;
    float s = 0.f;
    for (int d = 0; d < DH_; d++) s += (float)pw[d] * eb[d];
    be1p[t] = s;
}

// V[b][h][n] = x[b*N+n, :] . w[h, :]   — one wave per row, 4 heads at once
__global__ __launch_bounds__(256)
void compute_v(const _Float16* __restrict__ x, const float* __restrict__ w,
               float* __restrict__ V, int Kin)
{
    const int row  = blockIdx.x * 4 + (threadIdx.x >> 6);
    const int lane = threadIdx.x & 63;
    const int b = row >> 9, n = row & 511;
    const _Float16* xr = x + (size_t)row * Kin;
    float s0 = 0.f, s1 = 0.f, s2 = 0.f, s3 = 0.f;
    const int iters = Kin >> 6;
    for (int j = 0; j < iters; j++) {
        const int idx = lane + j * 64;
        const float xv = (float)xr[idx];
        s0 += xv * w[idx];
        s1 += xv * w[Kin + idx];
        s2 += xv * w[2 * Kin + idx];
        s3 += xv * w[3 * Kin + idx];
    }
#pragma unroll
    for (int off = 32; off; off >>= 1) {
        s0 += __shfl_xor(s0, off); s1 += __shfl_xor(s1, off);
        s2 += __shfl_xor(s2, off); s3 += __shfl_xor(s3, off);
    }
    if (lane == 0) {
        float* vb = V + ((size_t)b * H_) * N_ + n;
        vb[0] = s0; vb[N_] = s1; vb[2 * N_] = s2; vb[3 * N_] = s3;
    }
}

// ---------------------------------------------------------------------------
extern "C" void kernel_launch(void* const* d_in, const int* in_sizes, int n_in,
                              void* d_out, int out_size, void* d_ws, size_t ws_size,
                              hipStream_t stream)
{
    (void)in_sizes; (void)n_in; (void)out_size;

    const float* x      = (const float*)d_in[0];
    const float* e_w0   = (const float*)d_in[1];
    const float* e_b0   = (const float*)d_in[2];
    const float* kq_w0  = (const float*)d_in[3];
    const float* kq_b0  = (const float*)d_in[4];
    const float* e_w1   = (const float*)d_in[5];
    const float* e_b1   = (const float*)d_in[6];
    const float* kq_w1  = (const float*)d_in[7];
    const float* kq_b1  = (const float*)d_in[8];
    const float* proj_w = (const float*)d_in[9];
    const float* proj_b = (const float*)d_in[10];
    float* out = (float*)d_out;

    char* ws = (char*)d_ws;
    size_t off = 0;
    auto alloc = [&](size_t bytes) -> char* {
        char* p = ws + off;
        off += (bytes + 255) & ~(size_t)255;
        return p;
    };

    // persistent (~64 MB)
    _Float16* x16    = (_Float16*)alloc((size_t)BN_ * DIN_ * 2);
    _Float16* h1_16  = (_Float16*)alloc((size_t)BN_ * DH_ * 2);
    _Float16* kq0_16 = (_Float16*)alloc((size_t)H_ * DIN_ * 2 * DH_ * 2);
    _Float16* kq1_16 = (_Float16*)alloc((size_t)H_ * DH_ * 2 * DH_ * 2);
    _Float16* ew1_16 = (_Float16*)alloc((size_t)H_ * DH_ * DH_ * 2);
    _Float16* ewT0   = (_Float16*)alloc((size_t)H_ * DH_ * DIN_ * 2);
    _Float16* projwT = (_Float16*)alloc((size_t)DOUT_ * DH_ * 2);
    _Float16* Mt0    = (_Float16*)alloc((size_t)H_ * DIN_ * DIN_ * 2);
    _Float16* Mt1    = (_Float16*)alloc((size_t)H_ * DH_ * DH_ * 2);
    _Float16* We1pT  = (_Float16*)alloc((size_t)H_ * DOUT_ * DH_ * 2);
    float*    be1p   = (float*)alloc((size_t)H_ * DOUT_ * 4);
    float*    w0     = (float*)alloc((size_t)H_ * DIN_ * 4);
    float*    w1     = (float*)alloc((size_t)H_ * DH_ * 4);
    float*    Vb     = (float*)alloc((size_t)B_ * H_ * N_ * 4);

    const size_t persist = off;
    auto chunkBytes = [](int ch) {
        return (size_t)ch * N_ * H_ * DH_ * 2
             + (size_t)ch * H_ * N_ * N_ * 2
             + (size_t)ch * H_ * DH_ * N_ * 2;
    };
    int CH = 8;
    if (ws_size >= persist + chunkBytes(32) + (1u << 20)) CH = 32;
    else if (ws_size >= persist + chunkBytes(16) + (1u << 20)) CH = 16;
    const int NCH = B_ / CH;

    _Float16* Tc   = (_Float16*)alloc((size_t)CH * N_ * H_ * DH_ * 2);
    _Float16* Sc   = (_Float16*)alloc((size_t)CH * H_ * N_ * N_ * 2);
    _Float16* embc = (_Float16*)alloc((size_t)CH * H_ * DH_ * N_ * 2);

    auto gemm = [&](bool outF16,
                    const _Float16* A, long long aS1, long long aS2, int lda, long long aSeg,
                    const _Float16* Bp, long long bS1, long long bS2, int ldb, long long bSeg,
                    void* C, long long cS1, long long cS2, int ldc,
                    int M, int Nn, int K, int batches, int zShift,
                    const float* bias, int biasMode, long long biasS1, long long biasS2) {
        dim3 grid(Nn / 128, M / 128, batches), block(256);
        if (outF16)
            gemm_f16<true><<<grid, block, 0, stream>>>(A, aS1, aS2, lda, aSeg,
                Bp, bS1, bS2, ldb, bSeg, C, cS1, cS2, ldc, K, bias, biasMode, biasS1, biasS2, zShift);
        else
            gemm_f16<false><<<grid, block, 0, stream>>>(A, aS1, aS2, lda, aSeg,
                Bp, bS1, bS2, ldb, bSeg, C, cS1, cS2, ldc, K, bias, biasMode, biasS1, biasS2, zShift);
    };

    // --- preprocessing -----------------------------------------------------
    cvt_f32_f16<<<BN_ * DIN_ / 1024, 256, 0, stream>>>(x, x16);
    cvt_f32_f16<<<H_ * DIN_ * 2 * DH_ / 1024, 256, 0, stream>>>(kq_w0, kq0_16);
    cvt_f32_f16<<<H_ * DH_ * 2 * DH_ / 1024, 256, 0, stream>>>(kq_w1, kq1_16);
    cvt_f32_f16<<<H_ * DH_ * DH_ / 1024, 256, 0, stream>>>(e_w1, ew1_16);
    transpose_cvt<<<dim3(DH_ / 32, DIN_ / 32, H_), dim3(32, 8), 0, stream>>>(e_w0, ewT0, DIN_, DH_);
    transpose_cvt<<<dim3(DOUT_ / 32, DH_ / 32, 1), dim3(32, 8), 0, stream>>>(proj_w, projwT, DH_, DOUT_);

    // Mt_h = Wk_h * Wq_h^T  (so T = x * Mt^T = x * (Wq Wk^T))
    gemm(true, kq0_16, 0, (long long)DIN_ * 2 * DH_, 2 * DH_, 512,
         kq0_16 + DH_, 0, (long long)DIN_ * 2 * DH_, 2 * DH_, 512,
         Mt0, 0, (long long)DIN_ * DIN_, DIN_,
         DIN_, DIN_, DH_, H_, 2, nullptr, 0, 0, 0);
    gemm(true, kq1_16, 0, (long long)DH_ * 2 * DH_, 2 * DH_, 512,
         kq1_16 + DH_, 0, (long long)DH_ * 2 * DH_, 2 * DH_, 512,
         Mt1, 0, (long long)DH_ * DH_, DH_,
         DH_, DH_, DH_, H_, 2, nullptr, 0, 0, 0);
    // We1pT[h][o][d] = sum_d' projwT[o][d'] * e_w1[h][d][d']
    gemm(true, projwT, 0, 0, DH_, 512,
         ew1_16, 0, (long long)DH_ * DH_, DH_, 512,
         We1pT, 0, (long long)DOUT_ * DH_, DH_,
         DOUT_, DH_, DH_, H_, 2, nullptr, 0, 0, 0);
    fold_bias<<<H_ * DOUT_ / 256, 256, 0, stream>>>(projwT, e_b1, be1p);
    wk_bq<<<H_ * DIN_ / 256, 256, 0, stream>>>(kq_w0, kq_b0, w0, 8);
    wk_bq<<<H_ * DH_ / 256, 256, 0, stream>>>(kq_w1, kq_b1, w1, 9);

    const long long SB = (long long)N_ * N_;

    // --- two attention blocks ---------------------------------------------
    for (int blk = 0; blk < 2; blk++) {
        const _Float16* xin = blk ? h1_16 : x16;
        const int       Kin = blk ? DH_ : DIN_;
        const _Float16* Mt  = blk ? Mt1 : Mt0;
        const float*    wv  = blk ? w1 : w0;

        compute_v<<<BN_ / 4, 256, 0, stream>>>(xin, wv, Vb, Kin);

        for (int c = 0; c < NCH; c++) {
            const _Float16* xc = xin + (size_t)c * CH * N_ * Kin;

            // T[q, h*Kin+d'] = sum_d x[q,d] * Mt[h*Kin+d', d]
            gemm(true, xc, 0, 0, Kin, 512,
                 Mt, 0, 0, Kin, 512,
                 Tc, 0, 0, H_ * Kin,
                 CH * N_, H_ * Kin, Kin, 1, 0, nullptr, 0, 0, 0);
            // S[b][h][q][k] = T[b,h] * x_b^T + V[b][h][k]
            gemm(true, Tc, (long long)N_ * H_ * Kin, Kin, H_ * Kin, 512,
                 xc, (long long)N_ * Kin, 0, Kin, 512,
                 Sc, (long long)H_ * SB, SB, N_,
                 N_, N_, Kin, CH * H_, 2,
                 Vb + (size_t)c * CH * H_ * N_, 1, (long long)H_ * N_, N_);
            // P = softmax(S) * 0.25, in place fp16
            softmax_f16<<<CH * H_ * N_ / 4, 256, 0, stream>>>(Sc);

            if (blk == 0) {
                // embT[b][h*DH+e][n] = ewT0 @ x_b^T + e_b0
                gemm(true, ewT0, 0, 0, Kin, 512,
                     xc, (long long)N_ * Kin, 0, Kin, 512,
                     embc, (long long)H_ * DH_ * N_, 0, N_,
                     H_ * DH_, N_, Kin, CH, 0, e_b0, 2, 0, 0);
                // h1[b][q][e] = sum_{h,n} P * embT   (segmented K = H*N)
                gemm(true, Sc, (long long)H_ * SB, 0, N_, SB,
                     embc, (long long)H_ * DH_ * N_, 0, N_, (long long)DH_ * N_,
                     h1_16 + (size_t)c * CH * N_ * DH_, (long long)N_ * DH_, 0, DH_,
                     N_, DH_, H_ * N_, CH, 0, nullptr, 0, 0, 0);
            } else {
                // embWT[b][h*DOUT+o][n] = We1pT @ h1_b^T + be1p
                gemm(true, We1pT, 0, 0, DH_, 512,
                     xc, (long long)N_ * DH_, 0, DH_, 512,
                     embc, (long long)H_ * DOUT_ * N_, 0, N_,
                     H_ * DOUT_, N_, DH_, CH, 0, be1p, 2, 0, 0);
                // out[b][q][o] = sum_{h,n} P * embWT + proj_b  (fp32)
                gemm(false, Sc, (long long)H_ * SB, 0, N_, SB,
                     embc, (long long)H_ * DOUT_ * N_, 0, N_, (long long)DOUT_ * N_,
                     out + (size_t)c * CH * N_ * DOUT_, (long long)N_ * DOUT_, 0, DOUT_,
                     N_, DOUT_, H_ * N_, CH, 0, proj_b, 1, 0, 0);
            }
        }
    }
}

// Round 6
// 1099.536 us; speedup vs baseline: 2.1077x; 1.1052x over previous
//
#include <hip/hip_runtime.h>

typedef _Float16 half8 __attribute__((ext_vector_type(8)));
typedef _Float16 half4 __attribute__((ext_vector_type(4)));
typedef float floatx4 __attribute__((ext_vector_type(4)));

#define B_    64
#define N_    512
#define DIN_  256
#define DH_   512
#define DOUT_ 256
#define H_    4
#define BN_   (B_ * N_)   // 32768

// raw waitcnt immediates (gfx9: vmcnt[3:0]|[15:14], exp[6:4], lgkm[11:8])
#define WAIT_VM4_LGKM0() __builtin_amdgcn_s_waitcnt(0x0074)  // vm<=4, lgkm<=0
#define WAIT_VM0_LGKM0() __builtin_amdgcn_s_waitcnt(0x0070)  // vm<=0, lgkm<=0
#define MEMBAR()         __asm__ __volatile__("" ::: "memory")

__device__ static inline void async_copy16(const _Float16* g, _Float16* l) {
    __builtin_amdgcn_global_load_lds(
        (const __attribute__((address_space(1))) void*)g,
        (__attribute__((address_space(3))) void*)l, 16, 0, 0);
}

// ---------------------------------------------------------------------------
// GEMM: C[M,N] = A[M,K] * B[N,K]^T (+bias). fp16 in, fp16/fp32 out.
// Segmented K (512-elem segments): A elem (row,k) at z1*aS1 + z2*aS2
//   + row*lda + (k>>9)*aSeg + (k&511).  z1 = z>>zShift, z2 = z&mask.
// Tile 128x128, BK=32, 4 waves, 4x4 MFMA 16x16x32 f16, triple-buffered LDS,
// 2-iter-deep prefetch, one barrier/iter.
// LDS bank-conflict fix: global_load_lds forces linear LDS layout, so we
// permute WHICH 16B granule each lane fetches (scol XOR swizzle) and
// un-permute at ds_read time -> quad's 16 lanes cover all 8 bank groups 2x
// (2-way aliasing = free, m136).
// Epilogue: mfma(bf, af) swaps the C/D mapping so each lane's 4 acc regs are
// 4 CONSECUTIVE COLUMNS -> one 8B/16B store per subtile (16 stores vs 64).
// biasMode: 0 none, 1 bias[col], 2 bias[row]; bias += z1*biasS1 + z2*biasS2.
// ---------------------------------------------------------------------------
template <bool OUT_F16>
__global__ __launch_bounds__(256)
void gemm_f16(const _Float16* __restrict__ A, long long aS1, long long aS2, int lda, long long aSeg,
              const _Float16* __restrict__ B, long long bS1, long long bS2, int ldb, long long bSeg,
              void* __restrict__ Cv, long long cS1, long long cS2, int ldc,
              int K, const float* __restrict__ bias, int biasMode,
              long long biasS1, long long biasS2, int zShift)
{
    __shared__ __align__(16) _Float16 As[3][128 * 32];
    __shared__ __align__(16) _Float16 Bs[3][128 * 32];

    const int tid  = threadIdx.x;
    const int wave = tid >> 6;
    const int lane = tid & 63;
    const int quad = lane >> 4;
    const int r16  = lane & 15;

    const int z  = blockIdx.z;
    const int z1 = z >> zShift;
    const int z2 = z & ((1 << zShift) - 1);

    const int gx = gridDim.x, gy = gridDim.y;
    const int T = gx * gy;
    int lin = blockIdx.y * gx + blockIdx.x;
    int id2 = (T & 7) ? lin : ((lin & 7) * (T >> 3) + (lin >> 3));
    const int m0 = (id2 / gx) * 128;
    const int n0 = (id2 % gx) * 128;

    // staging with XOR-granule swizzle: lane (srow, g) fetches global granule
    // g ^ ((srow>>1)&3) of its row; LDS stays linear (HW constraint).
    const int srow = lane >> 2;                               // 0..15
    const int scol = (((lane & 3) ^ ((lane >> 3) & 3))) * 8;  // swizzled k-offs

    const _Float16* gaRow = A + z1 * aS1 + z2 * aS2
                              + (long long)(m0 + wave * 32 + srow) * lda + scol;
    const _Float16* gbRow = B + z1 * bS1 + z2 * bS2
                              + (long long)(n0 + wave * 32 + srow) * ldb + scol;

    const int wm = (wave >> 1) * 64;
    const int wn = (wave & 1) * 64;

    // un-swizzle at read: granule for global-k-group `quad` of row (..+r16)
    const int gl = (quad ^ ((r16 >> 1) & 3)) * 8;

    floatx4 acc[4][4];
#pragma unroll
    for (int i = 0; i < 4; i++)
#pragma unroll
        for (int j = 0; j < 4; j++) acc[i][j] = (floatx4){0.f, 0.f, 0.f, 0.f};

    auto stage = [&](int p, int k0) {
        const _Float16* a = gaRow + (long long)(k0 >> 9) * aSeg + (k0 & 511);
        const _Float16* b = gbRow + (long long)(k0 >> 9) * bSeg + (k0 & 511);
        _Float16* la = &As[p][wave * 1024];
        _Float16* lb = &Bs[p][wave * 1024];
        async_copy16(a,                    la);
        async_copy16(a + (size_t)16 * lda, la + 512);
        async_copy16(b,                    lb);
        async_copy16(b + (size_t)16 * ldb, lb + 512);
    };

    auto compute = [&](int p) {
        half8 af[4], bf[4];
#pragma unroll
        for (int i = 0; i < 4; i++)
            af[i] = *(const half8*)&As[p][(wm + i * 16 + r16) * 32 + gl];
#pragma unroll
        for (int j = 0; j < 4; j++)
            bf[j] = *(const half8*)&Bs[p][(wn + j * 16 + r16) * 32 + gl];
#pragma unroll
        for (int i = 0; i < 4; i++)
#pragma unroll
            for (int j = 0; j < 4; j++)
                acc[i][j] = __builtin_amdgcn_mfma_f32_16x16x32_f16(
                    bf[j], af[i], acc[i][j], 0, 0, 0);  // swapped: C^T layout
    };

    const int niter = K >> 5;           // >= 8 for all shapes here
    stage(0, 0);
    stage(1, 32);
    int pNext = 2;
    int pCur  = 0;
    for (int it = 0; it < niter - 1; ++it) {
        MEMBAR(); WAIT_VM4_LGKM0();
        __builtin_amdgcn_s_barrier();
        MEMBAR();
        if (it + 2 < niter) stage(pNext, (it + 2) << 5);
        compute(pCur);
        MEMBAR();
        pNext = (pNext == 2) ? 0 : pNext + 1;
        pCur  = (pCur  == 2) ? 0 : pCur  + 1;
    }
    MEMBAR(); WAIT_VM0_LGKM0();
    __builtin_amdgcn_s_barrier(); MEMBAR();
    compute(pCur);

    // epilogue (swapped layout): M = wm+i*16+r16, N = wn+j*16+quad*4+reg
    const float* bz = bias + z1 * biasS1 + z2 * biasS2;
    float*    Cf = (float*)Cv    + z1 * cS1 + z2 * cS2;
    _Float16* Ch = (_Float16*)Cv + z1 * cS1 + z2 * cS2;
#pragma unroll
    for (int i = 0; i < 4; i++) {
        const int row = m0 + wm + i * 16 + r16;
#pragma unroll
        for (int j = 0; j < 4; j++) {
            const int col = n0 + wn + j * 16 + quad * 4;
            float v0 = acc[i][j][0], v1 = acc[i][j][1],
                  v2 = acc[i][j][2], v3 = acc[i][j][3];
            if (biasMode == 1) {
                v0 += bz[col]; v1 += bz[col + 1];
                v2 += bz[col + 2]; v3 += bz[col + 3];
            } else if (biasMode == 2) {
                const float bv = bz[row];
                v0 += bv; v1 += bv; v2 += bv; v3 += bv;
            }
            const size_t idx = (size_t)row * ldc + col;
            if (OUT_F16) {
                half4 hv = {(_Float16)v0, (_Float16)v1, (_Float16)v2, (_Float16)v3};
                *(half4*)&Ch[idx] = hv;
            } else {
                float4 fv = {v0, v1, v2, v3};
                *(float4*)&Cf[idx] = fv;
            }
        }
    }
}

// ---------------------------------------------------------------------------
// in-place fp16 softmax over rows of 512, scaled by 0.25 (head mean).
// ---------------------------------------------------------------------------
__global__ __launch_bounds__(256)
void softmax_f16(_Float16* __restrict__ S)
{
    const int row  = blockIdx.x * 4 + (threadIdx.x >> 6);
    const int lane = threadIdx.x & 63;
    _Float16* s = S + (size_t)row * 512 + lane * 8;
    half8 h = *(const half8*)s;
    float v[8];
    float mx = -1e30f;
#pragma unroll
    for (int j = 0; j < 8; j++) { v[j] = (float)h[j]; mx = fmaxf(mx, v[j]); }
#pragma unroll
    for (int off = 32; off; off >>= 1) mx = fmaxf(mx, __shfl_xor(mx, off));
    float sum = 0.f;
#pragma unroll
    for (int j = 0; j < 8; j++) { v[j] = __expf(v[j] - mx); sum += v[j]; }
#pragma unroll
    for (int off = 32; off; off >>= 1) sum += __shfl_xor(sum, off);
    const float inv = 0.25f / sum;
#pragma unroll
    for (int j = 0; j < 8; j++) h[j] = (_Float16)(v[j] * inv);
    *(half8*)s = h;
}

__global__ __launch_bounds__(256)
void cvt_f32_f16(const float* __restrict__ in, _Float16* __restrict__ out)
{
    const size_t i = ((size_t)blockIdx.x * blockDim.x + threadIdx.x) * 4;
    const float4 f = *(const float4*)(in + i);
    out[i + 0] = (_Float16)f.x;
    out[i + 1] = (_Float16)f.y;
    out[i + 2] = (_Float16)f.z;
    out[i + 3] = (_Float16)f.w;
}

// in [G][R][C] -> out [G][C][R], fp32 -> fp16
__global__ __launch_bounds__(256)
void transpose_cvt(const float* __restrict__ in, _Float16* __restrict__ out,
                   int R, int C)
{
    __shared__ float tile[32][33];
    const int g  = blockIdx.z;
    const int c0 = blockIdx.x * 32;
    const int r0 = blockIdx.y * 32;
    const float* inp  = in  + (size_t)g * R * C;
    _Float16*    outp = out + (size_t)g * R * C;
#pragma unroll
    for (int i = threadIdx.y; i < 32; i += 8)
        tile[i][threadIdx.x] = inp[(size_t)(r0 + i) * C + c0 + threadIdx.x];
    __syncthreads();
#pragma unroll
    for (int i = threadIdx.y; i < 32; i += 8)
        outp[(size_t)(c0 + i) * R + r0 + threadIdx.x] = (_Float16)tile[threadIdx.x][i];
}

// w[h][d] = sum_e Wk[h][d][e] * bq[h][e]
__global__ __launch_bounds__(256)
void wk_bq(const float* __restrict__ kq_w, const float* __restrict__ kq_b,
           float* __restrict__ w, int dinShift)
{
    const int t = blockIdx.x * 256 + threadIdx.x;
    const int h = t >> dinShift;
    const int d = t & ((1 << dinShift) - 1);
    const float* wk = kq_w + ((size_t)(h << dinShift) + d) * (2 * DH_);
    const float* bq = kq_b + (size_t)h * 2 * DH_ + DH_;
    float s = 0.f;
    for (int e = 0; e < DH_; e++) s += wk[e] * bq[e];
    w[t] = s;
}

// be1p[h][o] = sum_d e_b1[h][d] * projwT[o][d]
__global__ __launch_bounds__(256)
void fold_bias(const _Float16* __restrict__ projwT, const float* __restrict__ e_b1,
               float* __restrict__ be1p)
{
    const int t = blockIdx.x * 256 + threadIdx.x;   // t < H*DOUT
    const int h = t >> 8;
    const int o = t & 255;
    const _Float16* pw = projwT + (size_t)o * DH_;
    const float*    eb = e_b1 + (size_t)h * DH_;
    float s = 0.f;
    for (int d = 0; d < DH_; d++) s += (float)pw[d] * eb[d];
    be1p[t] = s;
}

// V[b][h][n] = x[b*N+n, :] . w[h, :]   — one wave per row, 4 heads at once
__global__ __launch_bounds__(256)
void compute_v(const _Float16* __restrict__ x, const float* __restrict__ w,
               float* __restrict__ V, int Kin)
{
    const int row  = blockIdx.x * 4 + (threadIdx.x >> 6);
    const int lane = threadIdx.x & 63;
    const int b = row >> 9, n = row & 511;
    const _Float16* xr = x + (size_t)row * Kin;
    float s0 = 0.f, s1 = 0.f, s2 = 0.f, s3 = 0.f;
    const int iters = Kin >> 6;
    for (int j = 0; j < iters; j++) {
        const int idx = lane + j * 64;
        const float xv = (float)xr[idx];
        s0 += xv * w[idx];
        s1 += xv * w[Kin + idx];
        s2 += xv * w[2 * Kin + idx];
        s3 += xv * w[3 * Kin + idx];
    }
#pragma unroll
    for (int off = 32; off; off >>= 1) {
        s0 += __shfl_xor(s0, off); s1 += __shfl_xor(s1, off);
        s2 += __shfl_xor(s2, off); s3 += __shfl_xor(s3, off);
    }
    if (lane == 0) {
        float* vb = V + ((size_t)b * H_) * N_ + n;
        vb[0] = s0; vb[N_] = s1; vb[2 * N_] = s2; vb[3 * N_] = s3;
    }
}

// ---------------------------------------------------------------------------
extern "C" void kernel_launch(void* const* d_in, const int* in_sizes, int n_in,
                              void* d_out, int out_size, void* d_ws, size_t ws_size,
                              hipStream_t stream)
{
    (void)in_sizes; (void)n_in; (void)out_size;

    const float* x      = (const float*)d_in[0];
    const float* e_w0   = (const float*)d_in[1];
    const float* e_b0   = (const float*)d_in[2];
    const float* kq_w0  = (const float*)d_in[3];
    const float* kq_b0  = (const float*)d_in[4];
    const float* e_w1   = (const float*)d_in[5];
    const float* e_b1   = (const float*)d_in[6];
    const float* kq_w1  = (const float*)d_in[7];
    const float* kq_b1  = (const float*)d_in[8];
    const float* proj_w = (const float*)d_in[9];
    const float* proj_b = (const float*)d_in[10];
    float* out = (float*)d_out;

    char* ws = (char*)d_ws;
    size_t off = 0;
    auto alloc = [&](size_t bytes) -> char* {
        char* p = ws + off;
        off += (bytes + 255) & ~(size_t)255;
        return p;
    };

    // persistent (~64 MB)
    _Float16* x16    = (_Float16*)alloc((size_t)BN_ * DIN_ * 2);
    _Float16* h1_16  = (_Float16*)alloc((size_t)BN_ * DH_ * 2);
    _Float16* kq0_16 = (_Float16*)alloc((size_t)H_ * DIN_ * 2 * DH_ * 2);
    _Float16* kq1_16 = (_Float16*)alloc((size_t)H_ * DH_ * 2 * DH_ * 2);
    _Float16* ew1_16 = (_Float16*)alloc((size_t)H_ * DH_ * DH_ * 2);
    _Float16* ewT0   = (_Float16*)alloc((size_t)H_ * DH_ * DIN_ * 2);
    _Float16* projwT = (_Float16*)alloc((size_t)DOUT_ * DH_ * 2);
    _Float16* Mt0    = (_Float16*)alloc((size_t)H_ * DIN_ * DIN_ * 2);
    _Float16* Mt1    = (_Float16*)alloc((size_t)H_ * DH_ * DH_ * 2);
    _Float16* We1pT  = (_Float16*)alloc((size_t)H_ * DOUT_ * DH_ * 2);
    float*    be1p   = (float*)alloc((size_t)H_ * DOUT_ * 4);
    float*    w0     = (float*)alloc((size_t)H_ * DIN_ * 4);
    float*    w1     = (float*)alloc((size_t)H_ * DH_ * 4);
    float*    Vb     = (float*)alloc((size_t)B_ * H_ * N_ * 4);

    const size_t persist = off;
    auto chunkBytes = [](int ch) {
        return (size_t)ch * N_ * H_ * DH_ * 2
             + (size_t)ch * H_ * N_ * N_ * 2
             + (size_t)ch * H_ * DH_ * N_ * 2;
    };
    int CH = 8;
    if (ws_size >= persist + chunkBytes(32) + (1u << 20)) CH = 32;
    else if (ws_size >= persist + chunkBytes(16) + (1u << 20)) CH = 16;
    const int NCH = B_ / CH;

    _Float16* Tc   = (_Float16*)alloc((size_t)CH * N_ * H_ * DH_ * 2);
    _Float16* Sc   = (_Float16*)alloc((size_t)CH * H_ * N_ * N_ * 2);
    _Float16* embc = (_Float16*)alloc((size_t)CH * H_ * DH_ * N_ * 2);

    auto gemm = [&](bool outF16,
                    const _Float16* A, long long aS1, long long aS2, int lda, long long aSeg,
                    const _Float16* Bp, long long bS1, long long bS2, int ldb, long long bSeg,
                    void* C, long long cS1, long long cS2, int ldc,
                    int M, int Nn, int K, int batches, int zShift,
                    const float* bias, int biasMode, long long biasS1, long long biasS2) {
        dim3 grid(Nn / 128, M / 128, batches), block(256);
        if (outF16)
            gemm_f16<true><<<grid, block, 0, stream>>>(A, aS1, aS2, lda, aSeg,
                Bp, bS1, bS2, ldb, bSeg, C, cS1, cS2, ldc, K, bias, biasMode, biasS1, biasS2, zShift);
        else
            gemm_f16<false><<<grid, block, 0, stream>>>(A, aS1, aS2, lda, aSeg,
                Bp, bS1, bS2, ldb, bSeg, C, cS1, cS2, ldc, K, bias, biasMode, biasS1, biasS2, zShift);
    };

    // --- preprocessing -----------------------------------------------------
    cvt_f32_f16<<<BN_ * DIN_ / 1024, 256, 0, stream>>>(x, x16);
    cvt_f32_f16<<<H_ * DIN_ * 2 * DH_ / 1024, 256, 0, stream>>>(kq_w0, kq0_16);
    cvt_f32_f16<<<H_ * DH_ * 2 * DH_ / 1024, 256, 0, stream>>>(kq_w1, kq1_16);
    cvt_f32_f16<<<H_ * DH_ * DH_ / 1024, 256, 0, stream>>>(e_w1, ew1_16);
    transpose_cvt<<<dim3(DH_ / 32, DIN_ / 32, H_), dim3(32, 8), 0, stream>>>(e_w0, ewT0, DIN_, DH_);
    transpose_cvt<<<dim3(DOUT_ / 32, DH_ / 32, 1), dim3(32, 8), 0, stream>>>(proj_w, projwT, DH_, DOUT_);

    // Mt_h = Wk_h * Wq_h^T  (so T = x * Mt^T = x * (Wq Wk^T))
    gemm(true, kq0_16, 0, (long long)DIN_ * 2 * DH_, 2 * DH_, 512,
         kq0_16 + DH_, 0, (long long)DIN_ * 2 * DH_, 2 * DH_, 512,
         Mt0, 0, (long long)DIN_ * DIN_, DIN_,
         DIN_, DIN_, DH_, H_, 2, nullptr, 0, 0, 0);
    gemm(true, kq1_16, 0, (long long)DH_ * 2 * DH_, 2 * DH_, 512,
         kq1_16 + DH_, 0, (long long)DH_ * 2 * DH_, 2 * DH_, 512,
         Mt1, 0, (long long)DH_ * DH_, DH_,
         DH_, DH_, DH_, H_, 2, nullptr, 0, 0, 0);
    // We1pT[h][o][d] = sum_d' projwT[o][d'] * e_w1[h][d][d']
    gemm(true, projwT, 0, 0, DH_, 512,
         ew1_16, 0, (long long)DH_ * DH_, DH_, 512,
         We1pT, 0, (long long)DOUT_ * DH_, DH_,
         DOUT_, DH_, DH_, H_, 2, nullptr, 0, 0, 0);
    fold_bias<<<H_ * DOUT_ / 256, 256, 0, stream>>>(projwT, e_b1, be1p);
    wk_bq<<<H_ * DIN_ / 256, 256, 0, stream>>>(kq_w0, kq_b0, w0, 8);
    wk_bq<<<H_ * DH_ / 256, 256, 0, stream>>>(kq_w1, kq_b1, w1, 9);

    const long long SB = (long long)N_ * N_;

    // --- two attention blocks ---------------------------------------------
    for (int blk = 0; blk < 2; blk++) {
        const _Float16* xin = blk ? h1_16 : x16;
        const int       Kin = blk ? DH_ : DIN_;
        const _Float16* Mt  = blk ? Mt1 : Mt0;
        const float*    wv  = blk ? w1 : w0;

        compute_v<<<BN_ / 4, 256, 0, stream>>>(xin, wv, Vb, Kin);

        for (int c = 0; c < NCH; c++) {
            const _Float16* xc = xin + (size_t)c * CH * N_ * Kin;

            // T[q, h*Kin+d'] = sum_d x[q,d] * Mt[h*Kin+d', d]
            gemm(true, xc, 0, 0, Kin, 512,
                 Mt, 0, 0, Kin, 512,
                 Tc, 0, 0, H_ * Kin,
                 CH * N_, H_ * Kin, Kin, 1, 0, nullptr, 0, 0, 0);
            // S[b][h][q][k] = T[b,h] * x_b^T + V[b][h][k]
            gemm(true, Tc, (long long)N_ * H_ * Kin, Kin, H_ * Kin, 512,
                 xc, (long long)N_ * Kin, 0, Kin, 512,
                 Sc, (long long)H_ * SB, SB, N_,
                 N_, N_, Kin, CH * H_, 2,
                 Vb + (size_t)c * CH * H_ * N_, 1, (long long)H_ * N_, N_);
            // P = softmax(S) * 0.25, in place fp16
            softmax_f16<<<CH * H_ * N_ / 4, 256, 0, stream>>>(Sc);

            if (blk == 0) {
                // embT[b][h*DH+e][n] = ewT0 @ x_b^T + e_b0
                gemm(true, ewT0, 0, 0, Kin, 512,
                     xc, (long long)N_ * Kin, 0, Kin, 512,
                     embc, (long long)H_ * DH_ * N_, 0, N_,
                     H_ * DH_, N_, Kin, CH, 0, e_b0, 2, 0, 0);
                // h1[b][q][e] = sum_{h,n} P * embT   (segmented K = H*N)
                gemm(true, Sc, (long long)H_ * SB, 0, N_, SB,
                     embc, (long long)H_ * DH_ * N_, 0, N_, (long long)DH_ * N_,
                     h1_16 + (size_t)c * CH * N_ * DH_, (long long)N_ * DH_, 0, DH_,
                     N_, DH_, H_ * N_, CH, 0, nullptr, 0, 0, 0);
            } else {
                // embWT[b][h*DOUT+o][n] = We1pT @ h1_b^T + be1p
                gemm(true, We1pT, 0, 0, DH_, 512,
                     xc, (long long)N_ * DH_, 0, DH_, 512,
                     embc, (long long)H_ * DOUT_ * N_, 0, N_,
                     H_ * DOUT_, N_, DH_, CH, 0, be1p, 2, 0, 0);
                // out[b][q][o] = sum_{h,n} P * embWT + proj_b  (fp32)
                gemm(false, Sc, (long long)H_ * SB, 0, N_, SB,
                     embc, (long long)H_ * DOUT_ * N_, 0, N_, (long long)DOUT_ * N_,
                     out + (size_t)c * CH * N_ * DOUT_, (long long)N_ * DOUT_, 0, DOUT_,
                     N_, DOUT_, H_ * N_, CH, 0, proj_b, 1, 0, 0);
            }
        }
    }
}